// Round 1
// baseline (718.101 us; speedup 1.0000x reference)
//
#include <hip/hip_runtime.h>

// Problem constants (setup_inputs: B=64, N=4096, C=64, Cout=128, H=W=64)
#define BB 64
#define NN 4096
#define CCH 64
#define CO 128
#define HH 64
#define WW 64
#define H2 32
#define W2 32
#define NSC 1024
#define EPSF 1e-6f
#define BNEPS 1e-5f

typedef unsigned short ushort_t;
using bf8  = __attribute__((ext_vector_type(8))) short;   // 8 bf16 (4 VGPRs)
using f32x4 = __attribute__((ext_vector_type(4))) float;  // MFMA accumulator

__device__ inline ushort_t f2bf(float f) {
  unsigned u = __float_as_uint(f);
  unsigned r = (u + 0x7fffu + ((u >> 16) & 1u)) >> 16;  // RNE
  return (ushort_t)r;
}

__device__ inline void gload_lds16(const void* src, void* ldsdst) {
  __builtin_amdgcn_global_load_lds((const __attribute__((address_space(1))) void*)src,
                                   (__attribute__((address_space(3))) void*)ldsdst, 16, 0, 0);
}

// ---------- K1: point cells (64x64 and 32x32 grids) + idx_agg_down output ----------
__global__ __launch_bounds__(256) void k_prep(const float* __restrict__ loc,
                                              int* __restrict__ cell64, int* __restrict__ cell32,
                                              float* __restrict__ idx_out) {
  int i = blockIdx.x * 256 + threadIdx.x;  // exactly B*N
  float lx = loc[2 * i], ly = loc[2 * i + 1];
  lx = fminf(fmaxf(lx, -1.f), 1.f) * 0.5f + 0.5f;
  ly = fminf(fmaxf(ly, -1.f), 1.f) * 0.5f + 0.5f;
  int cx = (int)fminf(fmaxf(rintf(lx * (WW - 1)), 0.f), (float)(WW - 1));
  int cy = (int)fminf(fmaxf(rintf(ly * (HH - 1)), 0.f), (float)(HH - 1));
  cell64[i] = cx + cy * WW;
  int cx2 = (int)fminf(fmaxf(rintf(lx * (W2 - 1)), 0.f), (float)(W2 - 1));
  int cy2 = (int)fminf(fmaxf(rintf(ly * (H2 - 1)), 0.f), (float)(H2 - 1));
  int c2 = cx2 + cy2 * W2;
  cell32[i] = c2;
  idx_out[i] = (float)c2;
}

// ---------- K2: bf16 transposed weights for conv (wT[co][k=576]) and skip (swT[co][k=64]) ----------
__global__ __launch_bounds__(256) void k_wprep(const float* __restrict__ convw, const float* __restrict__ skipw,
                                               ushort_t* __restrict__ wT, ushort_t* __restrict__ swT) {
  int e = blockIdx.x * 256 + threadIdx.x;  // exactly 9*64*128 + 64*128 = 81920
  if (e < 9 * CCH * CO) {
    int co = e & 127, k = e >> 7;
    wT[co * 576 + k] = f2bf(convw[k * CO + co]);
  } else {
    int e2 = e - 9 * CCH * CO;
    int co = e2 & 127, k = e2 >> 7;
    swT[co * 64 + k] = f2bf(skipw[k * CO + co]);
  }
}

// ---------- K3: token2map scatter (feat = x[b, idx_agg], into 64x64 cells) ----------
__global__ __launch_bounds__(256) void k_t2m(const float* __restrict__ x, const int* __restrict__ idxagg,
                                             const int* __restrict__ cell64,
                                             float* __restrict__ xmap, float* __restrict__ cnt) {
  int t = blockIdx.x * 256 + threadIdx.x;  // B*N*64
  int c = t & 63, p = t >> 6;
  int b = p >> 12;
  int idx = idxagg[p];
  int cell = cell64[p];
  float v = x[(((size_t)b << 12) + idx) * 64 + c];
  unsafeAtomicAdd(&xmap[(((size_t)b << 12) + cell) * 64 + c], v);
  if (c == 0) unsafeAtomicAdd(&cnt[(b << 12) + cell], 1.0f);
}

// ---------- K4: x_map average + convert to padded bf16 map (B,66,66,64), border = 0 ----------
__global__ __launch_bounds__(256) void k_t2m_fin(const float* __restrict__ xmap, const float* __restrict__ cnt,
                                                 ushort_t* __restrict__ xmb) {
  int i4 = blockIdx.x * 256 + threadIdx.x;  // B*HW*C/4 = 4,194,304
  int c0 = (i4 & 15) * 4;
  int hw = (i4 >> 4) & 4095;
  int b = i4 >> 16;
  const float4 v = *(const float4*)&xmap[(size_t)i4 * 4];
  float inv = 1.0f / (cnt[(b << 12) + hw] + EPSF);
  int r = hw >> 6, cc = hw & 63;
  unsigned lo = (unsigned)f2bf(v.x * inv) | ((unsigned)f2bf(v.y * inv) << 16);
  unsigned hi = (unsigned)f2bf(v.z * inv) | ((unsigned)f2bf(v.w * inv) << 16);
  size_t o = (((size_t)(b * 66 + r + 1)) * 66 + cc + 1) * 64 + c0;
  *(uint2*)&xmb[o] = make_uint2(lo, hi);
}

// ---------- K5: x -> bf16 (for skip GEMM); aliases xmap region (runs after k_t2m_fin) ----------
__global__ __launch_bounds__(256) void k_xbf(const float* __restrict__ x, ushort_t* __restrict__ xbf) {
  int i4 = blockIdx.x * 256 + threadIdx.x;  // 4,194,304
  const float4 v = *(const float4*)&x[(size_t)i4 * 4];
  unsigned lo = (unsigned)f2bf(v.x) | ((unsigned)f2bf(v.y) << 16);
  unsigned hi = (unsigned)f2bf(v.z) | ((unsigned)f2bf(v.w) << 16);
  *(uint2*)&xbf[(size_t)i4 * 4] = make_uint2(lo, hi);
}

// ---------- K6: conv 3x3 stride2 pad1 as implicit GEMM, M=65536 K=576 N=128, bf16 MFMA ----------
// Block: 256 thr (4 waves), 128 M-rows x 128 N. LDS A-tile 128x32 bf16, double-buffered,
// XOR-swizzled 16B slots (write side pre-swizzles the GLOBAL source; gload_lds dest is linear).
__global__ __launch_bounds__(256) void k_conv(const ushort_t* __restrict__ xmb, const ushort_t* __restrict__ wT,
                                              const float* __restrict__ cb, float* __restrict__ y) {
  __shared__ ushort_t A[2][4096];  // 2 x 8KB
  const int tid = threadIdx.x;
  const int wave = tid >> 6, lane = tid & 63;
  const int m0 = blockIdx.x * 128;

  f32x4 acc[2][8];
  {
    float bv[8];
#pragma unroll
    for (int nt = 0; nt < 8; nt++) bv[nt] = cb[nt * 16 + (lane & 15)];
#pragma unroll
    for (int mt = 0; mt < 2; mt++)
#pragma unroll
      for (int nt = 0; nt < 8; nt++) {
        f32x4 a; a[0] = bv[nt]; a[1] = bv[nt]; a[2] = bv[nt]; a[3] = bv[nt];
        acc[mt][nt] = a;
      }
  }

  // staging geometry: q=0,1 chunks of 1KB per wave; row r = wave*32+q*16+(lane>>2), slot = lane&3
  // source slot pre-swizzled: slot_src = (lane&3) ^ ((r>>1)&3) = (lane&3) ^ ((lane>>3)&3)
  const int srcslot = (((lane & 3) ^ ((lane >> 3) & 3))) * 8;
  int sb[2], soy[2], sox[2];
#pragma unroll
  for (int q = 0; q < 2; q++) {
    int r = wave * 32 + q * 16 + (lane >> 2);
    int s = m0 + r;
    sb[q] = s >> 10; soy[q] = (s >> 5) & 31; sox[q] = s & 31;
  }

  auto stage = [&](int ks, int buf) {
    int kp = ks >> 1, ci0 = (ks & 1) * 32;
    int ky = kp / 3, kx = kp - ky * 3;
#pragma unroll
    for (int q = 0; q < 2; q++) {
      int iy = 2 * soy[q] + ky, ix = 2 * sox[q] + kx;  // padded coords (0..64)
      const ushort_t* src = xmb + (((size_t)sb[q] * 66 + iy) * 66 + ix) * 64 + ci0 + srcslot;
      gload_lds16(src, &A[buf][(wave * 32 + q * 16) * 32]);
    }
  };

  stage(0, 0);
  const int rdslotx = (lane >> 1) & 3;  // (r>>1)&3 for r = ...+(lane&15)
  for (int ks = 0; ks < 18; ks++) {
    int buf = ks & 1;
    __syncthreads();                    // stage(ks) landed; prev reads of buf^1 done
    if (ks < 17) stage(ks + 1, buf ^ 1);  // overlaps with compute below
    bf8 a[2];
#pragma unroll
    for (int mt = 0; mt < 2; mt++) {
      int r = wave * 32 + mt * 16 + (lane & 15);
      int slot = (lane >> 4) ^ rdslotx;
      a[mt] = *(const bf8*)&A[buf][r * 32 + slot * 8];
    }
    int k0 = ks * 32 + (lane >> 4) * 8;
#pragma unroll
    for (int nt = 0; nt < 8; nt++) {
      int co = nt * 16 + (lane & 15);
      bf8 bbf = *(const bf8*)&wT[co * 576 + k0];  // L2-resident
      acc[0][nt] = __builtin_amdgcn_mfma_f32_16x16x32_bf16(a[0], bbf, acc[0][nt], 0, 0, 0);
      acc[1][nt] = __builtin_amdgcn_mfma_f32_16x16x32_bf16(a[1], bbf, acc[1][nt], 0, 0, 0);
    }
  }
#pragma unroll
  for (int mt = 0; mt < 2; mt++)
#pragma unroll
    for (int nt = 0; nt < 8; nt++) {
      int co = nt * 16 + (lane & 15);
#pragma unroll
      for (int j = 0; j < 4; j++) {
        int srow = m0 + wave * 32 + mt * 16 + (lane >> 4) * 4 + j;
        y[(size_t)srow * 128 + co] = acc[mt][nt][j];
      }
    }
}

// ---------- K7: map2token scatter: xt_num[b, idx_agg] += y[b, cell32] * aw ----------
__global__ __launch_bounds__(256) void k_m2t(const float* __restrict__ y, const float* __restrict__ aw,
                                             const int* __restrict__ idxagg, const int* __restrict__ cell32,
                                             float* __restrict__ XT, float* __restrict__ nrm) {
  int t = blockIdx.x * 256 + threadIdx.x;  // B*N*128
  int c = t & 127, p = t >> 7;
  int b = p >> 12;
  int idx = idxagg[p];
  int cell = cell32[p];
  float v = aw[p];
  float f = y[(((size_t)b << 10) + cell) * 128 + c] * v;
  unsafeAtomicAdd(&XT[(((size_t)b << 12) + idx) * 128 + c], f);
  if (c == 0) unsafeAtomicAdd(&nrm[(b << 12) + idx], v);
}

// ---------- K8: xt = xt_num/(norm+eps) + x @ skip_w (bf16 MFMA, M=262144 K=64 N=128) ----------
__global__ __launch_bounds__(256) void k_xt(const ushort_t* __restrict__ xbf, const ushort_t* __restrict__ swT,
                                            float* __restrict__ XT, const float* __restrict__ nrm) {
  __shared__ ushort_t A[8192];  // 128 rows x 64 bf16 = 16KB
  const int tid = threadIdx.x, wave = tid >> 6, lane = tid & 63;
  const int t0 = blockIdx.x * 128;
  const int srcslot = ((lane & 7) ^ (lane >> 3)) * 8;  // slot ^ (r&7)
#pragma unroll
  for (int q = 0; q < 4; q++) {
    int chunk = wave * 4 + q;
    int r = chunk * 8 + (lane >> 3);
    const ushort_t* src = xbf + ((size_t)(t0 + r)) * 64 + srcslot;
    gload_lds16(src, &A[chunk * 512]);
  }
  __syncthreads();
  f32x4 acc[2][8];
#pragma unroll
  for (int mt = 0; mt < 2; mt++)
#pragma unroll
    for (int nt = 0; nt < 8; nt++) { f32x4 z; z[0] = 0; z[1] = 0; z[2] = 0; z[3] = 0; acc[mt][nt] = z; }
#pragma unroll
  for (int ks = 0; ks < 2; ks++) {
    bf8 a[2];
#pragma unroll
    for (int mt = 0; mt < 2; mt++) {
      int r = wave * 32 + mt * 16 + (lane & 15);
      int slot = (ks * 4 + (lane >> 4)) ^ (lane & 7);
      a[mt] = *(const bf8*)&A[r * 64 + slot * 8];
    }
#pragma unroll
    for (int nt = 0; nt < 8; nt++) {
      int co = nt * 16 + (lane & 15);
      bf8 bbf = *(const bf8*)&swT[co * 64 + ks * 32 + (lane >> 4) * 8];
      acc[0][nt] = __builtin_amdgcn_mfma_f32_16x16x32_bf16(a[0], bbf, acc[0][nt], 0, 0, 0);
      acc[1][nt] = __builtin_amdgcn_mfma_f32_16x16x32_bf16(a[1], bbf, acc[1][nt], 0, 0, 0);
    }
  }
#pragma unroll
  for (int mt = 0; mt < 2; mt++)
#pragma unroll
    for (int nt = 0; nt < 8; nt++) {
      int co = nt * 16 + (lane & 15);
#pragma unroll
      for (int j = 0; j < 4; j++) {
        int t = t0 + wave * 32 + mt * 16 + (lane >> 4) * 4 + j;
        size_t o = (size_t)t * 128 + co;
        XT[o] = acc[mt][nt][j] + XT[o] / (nrm[t] + EPSF);
      }
    }
}

// ---------- K9: BN batch stats (sum, sumsq per channel) ----------
__global__ __launch_bounds__(256) void k_bnstats(const float* __restrict__ XT, float* __restrict__ bn) {
  int tid = threadIdx.x;
  int c = tid & 127, h = tid >> 7;
  float s = 0.f, q = 0.f;
  for (int p = blockIdx.x * 2 + h; p < BB * NN; p += 2048) {
    float v = XT[(size_t)p * 128 + c];
    s += v; q += v * v;
  }
  __shared__ float red[256];
  red[tid] = s; __syncthreads();
  if (tid < 128) red[tid] += red[tid + 128];
  __syncthreads();
  if (tid < 128) unsafeAtomicAdd(&bn[tid], red[tid]);
  __syncthreads();
  red[tid] = q; __syncthreads();
  if (tid < 128) red[tid] += red[tid + 128];
  __syncthreads();
  if (tid < 128) unsafeAtomicAdd(&bn[128 + tid], red[tid]);
}

// ---------- K10: per-channel scale/shift ----------
__global__ void k_bnfin(const float* __restrict__ bn, const float* __restrict__ gamma,
                        const float* __restrict__ beta, float* __restrict__ ss) {
  int c = threadIdx.x;  // 128
  float n = (float)(BB * NN);
  float mean = bn[c] / n;
  float var = bn[128 + c] / n - mean * mean;
  float sc = gamma[c] * rsqrtf(var + BNEPS);
  ss[c] = sc;
  ss[128 + c] = beta[c] - mean * sc;
}

// ---------- K11: conf = xtn @ conf_w + b ; weight = exp(conf) (one wave per token) ----------
__global__ __launch_bounds__(256) void k_conf(const float* __restrict__ XT, const float* __restrict__ ss,
                                              const float* __restrict__ confw, const float* __restrict__ confb,
                                              float* __restrict__ conf_out, float* __restrict__ wgt) {
  int gid = blockIdx.x * 256 + threadIdx.x;
  int p = gid >> 6, lane = gid & 63;
  const float* row = XT + (size_t)p * 128;
  float v0 = row[lane] * ss[lane] + ss[128 + lane];
  float v1 = row[64 + lane] * ss[64 + lane] + ss[192 + lane];
  float s = v0 * confw[lane] + v1 * confw[64 + lane];
#pragma unroll
  for (int off = 32; off; off >>= 1) s += __shfl_down(s, off, 64);
  if (lane == 0) {
    float cf = s + confb[0];
    conf_out[p] = cf;
    wgt[p] = __expf(cf) ;
  }
}

// ---------- K12: cluster scatter: xd[b, cell32] += xtn[b, idx_agg] * w[b, idx_agg] ----------
__global__ __launch_bounds__(256) void k_cluster(const float* __restrict__ XT, const float* __restrict__ ss,
                                                 const float* __restrict__ wgt, const int* __restrict__ idxagg,
                                                 const int* __restrict__ cell32,
                                                 float* __restrict__ xd, float* __restrict__ cnrm) {
  int t = blockIdx.x * 256 + threadIdx.x;  // B*N*128
  int c = t & 127, p = t >> 7;
  int b = p >> 12;
  int idx = idxagg[p];
  int cell = cell32[p];
  float v = wgt[(b << 12) + idx];
  float xv = XT[(((size_t)b << 12) + idx) * 128 + c];
  float f = (xv * ss[c] + ss[128 + c]) * v;
  unsafeAtomicAdd(&xd[(((size_t)b << 10) + cell) * 128 + c], f);
  if (c == 0) unsafeAtomicAdd(&cnrm[(b << 10) + cell], v);
}

// ---------- K13: x_down = relu(s / (cnorm+eps)) in place ----------
__global__ __launch_bounds__(256) void k_xdownfin(float* __restrict__ xd, const float* __restrict__ cnrm) {
  int i4 = blockIdx.x * 256 + threadIdx.x;  // 2,097,152
  float4 v = *(float4*)&xd[(size_t)i4 * 4];
  float inv = 1.f / (cnrm[i4 >> 5] + EPSF);
  v.x = fmaxf(v.x * inv, 0.f); v.y = fmaxf(v.y * inv, 0.f);
  v.z = fmaxf(v.z * inv, 0.f); v.w = fmaxf(v.w * inv, 0.f);
  *(float4*)&xd[(size_t)i4 * 4] = v;
}

// ---------- K14: agg_weight_down (pre-norm) + per-batch max ----------
__global__ __launch_bounds__(256) void k_awd(const float* __restrict__ wgt, const float* __restrict__ aw,
                                             const int* __restrict__ idxagg, const int* __restrict__ cell32,
                                             const float* __restrict__ cnrm,
                                             float* __restrict__ awd, int* __restrict__ maxb) {
  int p = blockIdx.x * 256 + threadIdx.x;  // B*N
  int b = p >> 12;
  float v = wgt[(b << 12) + idxagg[p]];
  float wt = v / (cnrm[(b << 10) + cell32[p]] + EPSF);
  float a = aw[p] * wt;
  awd[p] = a;
  float m = a;
#pragma unroll
  for (int off = 32; off; off >>= 1) m = fmaxf(m, __shfl_down(m, off, 64));
  if ((threadIdx.x & 63) == 0) atomicMax(&maxb[b], __float_as_int(m));  // all values > 0
}

// ---------- K15: normalize awd by per-batch max ----------
__global__ __launch_bounds__(256) void k_awdnorm(float* __restrict__ awd, const int* __restrict__ maxb) {
  int p = blockIdx.x * 256 + threadIdx.x;
  int b = p >> 12;
  awd[p] = awd[p] / __int_as_float(maxb[b]);
}

// ---------- K16: x_act = relu(xt * scale + shift) in place ----------
__global__ __launch_bounds__(256) void k_xact(float* __restrict__ XT, const float* __restrict__ ss) {
  int i4 = blockIdx.x * 256 + threadIdx.x;  // 8,388,608
  int c0 = (i4 & 31) * 4;
  float4 v = *(float4*)&XT[(size_t)i4 * 4];
  const float4 sc = *(const float4*)&ss[c0];
  const float4 sh = *(const float4*)&ss[128 + c0];
  v.x = fmaxf(v.x * sc.x + sh.x, 0.f);
  v.y = fmaxf(v.y * sc.y + sh.y, 0.f);
  v.z = fmaxf(v.z * sc.z + sh.z, 0.f);
  v.w = fmaxf(v.w * sc.w + sh.w, 0.f);
  *(float4*)&XT[(size_t)i4 * 4] = v;
}

extern "C" void kernel_launch(void* const* d_in, const int* in_sizes, int n_in,
                              void* d_out, int out_size, void* d_ws, size_t ws_size,
                              hipStream_t stream) {
  (void)in_sizes; (void)n_in; (void)out_size;
  const float* x      = (const float*)d_in[0];
  const float* loc    = (const float*)d_in[1];
  const int*   idxagg = (const int*)  d_in[2];
  const float* aw     = (const float*)d_in[3];
  const float* convw  = (const float*)d_in[4];
  const float* convb  = (const float*)d_in[5];
  const float* skipw  = (const float*)d_in[6];
  const float* gamma  = (const float*)d_in[7];
  const float* beta   = (const float*)d_in[8];
  const float* confw  = (const float*)d_in[9];
  const float* confb  = (const float*)d_in[10];

  char* ws = (char*)d_ws;
  // ws layout (bytes). xbf aliases xmap (used only after k_t2m_fin).
  float*    XMAP = (float*)(ws + 0);            // 67,108,864 B
  ushort_t* XBF  = (ushort_t*)(ws + 0);         // 33,554,432 B (alias)
  float*    Y    = (float*)(ws + 67108864);     // 33,554,432 B
  ushort_t* XMB  = (ushort_t*)(ws + 100663296); // 35,684,352 B (padded 66x66 map)
  ushort_t* WT   = (ushort_t*)(ws + 136347648); // 147,456 B
  ushort_t* SWT  = (ushort_t*)(ws + 136495104); // 16,384 B
  float*    NORM = (float*)(ws + 136511488);    // 1,048,576 B
  float*    CNT  = (float*)(ws + 137560064);    // 1,048,576 B
  float*    WGT  = (float*)(ws + 138608640);    // 1,048,576 B
  int*      CL64 = (int*)  (ws + 139657216);    // 1,048,576 B
  int*      CL32 = (int*)  (ws + 140705792);    // 1,048,576 B
  float*    CNRM = (float*)(ws + 141754368);    // 262,144 B
  float*    BN   = (float*)(ws + 142016512);    // 1,024 B
  float*    SS   = (float*)(ws + 142017536);    // 1,024 B
  int*      MAXB = (int*)  (ws + 142018560);    // 256 B
  if (ws_size < 142018816) return;  // insufficient workspace -> visible failure

  float* out    = (float*)d_out;
  float* O_XD   = out;               // x_down: 8,388,608 floats
  float* O_IDX  = out + 8388608;     // idx_agg_down (as float): 262,144
  float* O_AWD  = out + 8650752;     // agg_weight_down: 262,144
  float* XT     = out + 8912896;     // x_act region; holds xt pre-BN until k_xact
  float* O_CONF = out + 42467328;    // conf: 262,144

  // zero accumulators / padded borders
  hipMemsetAsync(XMAP, 0, 67108864, stream);
  hipMemsetAsync(XMB, 0, 35684352, stream);
  hipMemsetAsync(NORM, 0, 1048576, stream);
  hipMemsetAsync(CNT, 0, 1048576, stream);
  hipMemsetAsync(CNRM, 0, 262144, stream);
  hipMemsetAsync(BN, 0, 1024, stream);
  hipMemsetAsync(MAXB, 0, 256, stream);
  hipMemsetAsync(XT, 0, 134217728, stream);
  hipMemsetAsync(O_XD, 0, 33554432, stream);

  k_prep   <<<1024,   256, 0, stream>>>(loc, CL64, CL32, O_IDX);
  k_wprep  <<<320,    256, 0, stream>>>(convw, skipw, WT, SWT);
  k_t2m    <<<65536,  256, 0, stream>>>(x, idxagg, CL64, XMAP, CNT);
  k_t2m_fin<<<16384,  256, 0, stream>>>(XMAP, CNT, XMB);
  k_xbf    <<<16384,  256, 0, stream>>>(x, XBF);           // after t2m_fin (aliases XMAP)
  k_conv   <<<512,    256, 0, stream>>>(XMB, WT, convb, Y);
  k_m2t    <<<131072, 256, 0, stream>>>(Y, aw, idxagg, CL32, XT, NORM);
  k_xt     <<<2048,   256, 0, stream>>>(XBF, SWT, XT, NORM);
  k_bnstats<<<1024,   256, 0, stream>>>(XT, BN);
  k_bnfin  <<<1,      128, 0, stream>>>(BN, gamma, beta, SS);
  k_conf   <<<65536,  256, 0, stream>>>(XT, SS, confw, confb, O_CONF, WGT);
  k_cluster<<<131072, 256, 0, stream>>>(XT, SS, WGT, idxagg, CL32, O_XD, CNRM);
  k_xdownfin<<<8192,  256, 0, stream>>>(O_XD, CNRM);
  k_awd    <<<1024,   256, 0, stream>>>(WGT, aw, idxagg, CL32, CNRM, O_AWD, MAXB);
  k_awdnorm<<<1024,   256, 0, stream>>>(O_AWD, MAXB);
  k_xact   <<<32768,  256, 0, stream>>>(XT, SS);
}

// Round 2
// 603.014 us; speedup vs baseline: 1.1909x; 1.1909x over previous
//
#include <hip/hip_runtime.h>

// Problem constants (setup_inputs: B=64, N=4096, C=64, Cout=128, H=W=64)
#define BB 64
#define NN 4096
#define CCH 64
#define CO 128
#define HH 64
#define WW 64
#define H2 32
#define W2 32
#define EPSF 1e-6f
#define BNEPS 1e-5f

typedef unsigned short ushort_t;
using bf8  = __attribute__((ext_vector_type(8))) short;   // 8 bf16 (4 VGPRs)
using f32x4 = __attribute__((ext_vector_type(4))) float;  // MFMA accumulator

__device__ inline ushort_t f2bf(float f) {
  unsigned u = __float_as_uint(f);
  unsigned r = (u + 0x7fffu + ((u >> 16) & 1u)) >> 16;  // RNE
  return (ushort_t)r;
}

__device__ inline void gload_lds16(const void* src, void* ldsdst) {
  __builtin_amdgcn_global_load_lds((const __attribute__((address_space(1))) void*)src,
                                   (__attribute__((address_space(3))) void*)ldsdst, 16, 0, 0);
}

// ---------- K1: point cells + idx_agg_down output + count phase of 3 sorts ----------
__global__ __launch_bounds__(256) void k_prep(const float* __restrict__ loc, const int* __restrict__ idxagg,
                                              int* __restrict__ cell64, int* __restrict__ cell32,
                                              float* __restrict__ idx_out,
                                              int* __restrict__ cnt64, int* __restrict__ cnt32,
                                              int* __restrict__ cntT) {
  int i = blockIdx.x * 256 + threadIdx.x;  // exactly B*N = 262144
  int b = i >> 12;
  float lx = loc[2 * i], ly = loc[2 * i + 1];
  lx = fminf(fmaxf(lx, -1.f), 1.f) * 0.5f + 0.5f;
  ly = fminf(fmaxf(ly, -1.f), 1.f) * 0.5f + 0.5f;
  int cx = (int)fminf(fmaxf(rintf(lx * (WW - 1)), 0.f), (float)(WW - 1));
  int cy = (int)fminf(fmaxf(rintf(ly * (HH - 1)), 0.f), (float)(HH - 1));
  int c64 = cx + cy * WW;
  cell64[i] = c64;
  int cx2 = (int)fminf(fmaxf(rintf(lx * (W2 - 1)), 0.f), (float)(W2 - 1));
  int cy2 = (int)fminf(fmaxf(rintf(ly * (H2 - 1)), 0.f), (float)(H2 - 1));
  int c2 = cx2 + cy2 * W2;
  cell32[i] = c2;
  idx_out[i] = (float)c2;
  atomicAdd(&cnt64[(b << 12) + c64], 1);
  atomicAdd(&cnt32[(b << 10) + c2], 1);
  atomicAdd(&cntT[(b << 12) + idxagg[i]], 1);
}

// ---------- K2: bf16 transposed weights ----------
__global__ __launch_bounds__(256) void k_wprep(const float* __restrict__ convw, const float* __restrict__ skipw,
                                               ushort_t* __restrict__ wT, ushort_t* __restrict__ swT) {
  int e = blockIdx.x * 256 + threadIdx.x;  // 9*64*128 + 64*128 = 81920
  if (e < 9 * CCH * CO) {
    int co = e & 127, k = e >> 7;
    wT[co * 576 + k] = f2bf(convw[k * CO + co]);
  } else {
    int e2 = e - 9 * CCH * CO;
    int co = e2 & 127, k = e2 >> 7;
    swT[co * 64 + k] = f2bf(skipw[k * CO + co]);
  }
}

// ---------- scan helper: exclusive prefix over L (multiple of 256) ints, 256 threads ----------
__device__ void block_exscan(const int* __restrict__ in, int* __restrict__ out, int* __restrict__ cur, int L) {
  __shared__ int partial[256];
  int tid = threadIdx.x;
  int per = L >> 8;
  int base = tid * per;
  int s = 0;
  for (int i = 0; i < per; i++) s += in[base + i];
  __syncthreads();  // protect partial[] from previous call
  partial[tid] = s;
  __syncthreads();
  for (int d = 1; d < 256; d <<= 1) {
    int v = (tid >= d) ? partial[tid - d] : 0;
    __syncthreads();
    partial[tid] += v;
    __syncthreads();
  }
  int run = (tid == 0) ? 0 : partial[tid - 1];
  for (int i = 0; i < per; i++) {
    out[base + i] = run;
    cur[base + i] = run;
    run += in[base + i];
  }
}

// ---------- K3: per-batch prefix scans for the 3 sorts ----------
__global__ __launch_bounds__(256) void k_scan(const int* __restrict__ cnt64, int* __restrict__ off64, int* __restrict__ cur64,
                                              const int* __restrict__ cntT, int* __restrict__ offT, int* __restrict__ curT,
                                              const int* __restrict__ cnt32, int* __restrict__ off32, int* __restrict__ cur32) {
  int b = blockIdx.x;  // 64
  block_exscan(cnt64 + ((size_t)b << 12), off64 + ((size_t)b << 12), cur64 + ((size_t)b << 12), 4096);
  block_exscan(cntT + ((size_t)b << 12), offT + ((size_t)b << 12), curT + ((size_t)b << 12), 4096);
  block_exscan(cnt32 + ((size_t)b << 10), off32 + ((size_t)b << 10), cur32 + ((size_t)b << 10), 1024);
}

// ---------- K4: fill sorted point lists ----------
__global__ __launch_bounds__(256) void k_fill(const int* __restrict__ idxagg, const int* __restrict__ cl64,
                                              const int* __restrict__ cl32,
                                              int* __restrict__ cur64, int* __restrict__ curT, int* __restrict__ cur32,
                                              int* __restrict__ list64, int* __restrict__ listT, int* __restrict__ list32) {
  int i = blockIdx.x * 256 + threadIdx.x;  // B*N
  int b = i >> 12, p = i & 4095;
  int pos = atomicAdd(&cur64[(b << 12) + cl64[i]], 1);
  list64[(b << 12) + pos] = p;
  pos = atomicAdd(&curT[(b << 12) + idxagg[i]], 1);
  listT[(b << 12) + pos] = p;
  pos = atomicAdd(&cur32[(b << 10) + cl32[i]], 1);
  list32[(b << 12) + pos] = p;
}

// ---------- K5: token2map as GATHER: one wave per 64x64 cell, write padded bf16 map ----------
__global__ __launch_bounds__(256) void k_t2m(const float* __restrict__ x, const int* __restrict__ idxagg,
                                             const int* __restrict__ cnt64, const int* __restrict__ off64,
                                             const int* __restrict__ list64, ushort_t* __restrict__ xmb) {
  int blk = blockIdx.x;                       // 65536
  int sblk = (blk & 7) * 8192 + (blk >> 3);   // XCD swizzle: batch-contiguous per XCD
  int g = sblk * 4 + (threadIdx.x >> 6);      // cell id in [0, 64*4096)
  int lane = threadIdx.x & 63;
  int b = g >> 12, cell = g & 4095;
  int n = cnt64[g], o = off64[g];
  float sum = 0.f;
  for (int i = 0; i < n; i++) {
    int p = list64[(b << 12) + o + i];
    int idx = idxagg[(b << 12) + p];
    sum += x[((size_t)((b << 12) + idx)) * 64 + lane];
  }
  float avg = sum / ((float)n + EPSF);
  int r = cell >> 6, cc = cell & 63;
  xmb[(((size_t)(b * 66 + r + 1)) * 66 + cc + 1) * 64 + lane] = f2bf(avg);
}

// ---------- K6: conv 3x3 stride2 pad1 implicit GEMM (unchanged, verified) ----------
__global__ __launch_bounds__(256) void k_conv(const ushort_t* __restrict__ xmb, const ushort_t* __restrict__ wT,
                                              const float* __restrict__ cb, float* __restrict__ y) {
  __shared__ ushort_t A[2][4096];
  const int tid = threadIdx.x;
  const int wave = tid >> 6, lane = tid & 63;
  const int m0 = blockIdx.x * 128;

  f32x4 acc[2][8];
  {
    float bv[8];
#pragma unroll
    for (int nt = 0; nt < 8; nt++) bv[nt] = cb[nt * 16 + (lane & 15)];
#pragma unroll
    for (int mt = 0; mt < 2; mt++)
#pragma unroll
      for (int nt = 0; nt < 8; nt++) {
        f32x4 a; a[0] = bv[nt]; a[1] = bv[nt]; a[2] = bv[nt]; a[3] = bv[nt];
        acc[mt][nt] = a;
      }
  }

  const int srcslot = (((lane & 3) ^ ((lane >> 3) & 3))) * 8;
  int sb[2], soy[2], sox[2];
#pragma unroll
  for (int q = 0; q < 2; q++) {
    int r = wave * 32 + q * 16 + (lane >> 2);
    int s = m0 + r;
    sb[q] = s >> 10; soy[q] = (s >> 5) & 31; sox[q] = s & 31;
  }

  auto stage = [&](int ks, int buf) {
    int kp = ks >> 1, ci0 = (ks & 1) * 32;
    int ky = kp / 3, kx = kp - ky * 3;
#pragma unroll
    for (int q = 0; q < 2; q++) {
      int iy = 2 * soy[q] + ky, ix = 2 * sox[q] + kx;
      const ushort_t* src = xmb + (((size_t)sb[q] * 66 + iy) * 66 + ix) * 64 + ci0 + srcslot;
      gload_lds16(src, &A[buf][(wave * 32 + q * 16) * 32]);
    }
  };

  stage(0, 0);
  const int rdslotx = (lane >> 1) & 3;
  for (int ks = 0; ks < 18; ks++) {
    int buf = ks & 1;
    __syncthreads();
    if (ks < 17) stage(ks + 1, buf ^ 1);
    bf8 a[2];
#pragma unroll
    for (int mt = 0; mt < 2; mt++) {
      int r = wave * 32 + mt * 16 + (lane & 15);
      int slot = (lane >> 4) ^ rdslotx;
      a[mt] = *(const bf8*)&A[buf][r * 32 + slot * 8];
    }
    int k0 = ks * 32 + (lane >> 4) * 8;
#pragma unroll
    for (int nt = 0; nt < 8; nt++) {
      int co = nt * 16 + (lane & 15);
      bf8 bbf = *(const bf8*)&wT[co * 576 + k0];
      acc[0][nt] = __builtin_amdgcn_mfma_f32_16x16x32_bf16(a[0], bbf, acc[0][nt], 0, 0, 0);
      acc[1][nt] = __builtin_amdgcn_mfma_f32_16x16x32_bf16(a[1], bbf, acc[1][nt], 0, 0, 0);
    }
  }
#pragma unroll
  for (int mt = 0; mt < 2; mt++)
#pragma unroll
    for (int nt = 0; nt < 8; nt++) {
      int co = nt * 16 + (lane & 15);
#pragma unroll
      for (int j = 0; j < 4; j++) {
        int srow = m0 + wave * 32 + mt * 16 + (lane >> 4) * 4 + j;
        y[(size_t)srow * 128 + co] = acc[mt][nt][j];
      }
    }
}

// ---------- K7: FUSED xt = gather_m2t(y)/norm + x@skip_w, write XT once, BN partial sums ----------
__global__ __launch_bounds__(256) void k_xt(const float* __restrict__ x, const ushort_t* __restrict__ swT,
                                            const float* __restrict__ y, const float* __restrict__ aw,
                                            const int* __restrict__ idxagg, const int* __restrict__ cl32,
                                            const int* __restrict__ offT, const int* __restrict__ listT,
                                            float* __restrict__ XT, float* __restrict__ BN) {
  __shared__ float xg[128 * 130];   // 66560 B; first 32KB doubles as f32 x staging
  __shared__ float nrmsh[128];
  __shared__ float bnred[256];
  const int tid = threadIdx.x, wave = tid >> 6, lane = tid & 63;
  int blk = blockIdx.x;                      // 2048
  int sblk = (blk & 7) * 256 + (blk >> 3);   // XCD swizzle (8 batches per XCD)
  const int t0 = sblk * 128;
  const int b = t0 >> 12, lt0 = t0 & 4095;

  // ---- stage x f32 128x64, 16B slots swizzled: dest slot s' holds source slot s'^(r&7)
#pragma unroll
  for (int qq = 0; qq < 2; qq++) {
    int q = wave * 2 + qq;
    int r = q * 16 + (lane >> 4);
    int sp = lane & 15;
    const float* src = x + ((size_t)(t0 + r)) * 64 + ((sp ^ (r & 7)) << 2);
    gload_lds16(src, (char*)xg + q * 4096);
  }
  __syncthreads();

  // ---- A fragments: read swizzled slots, convert f32->bf16
  bf8 afr[2][2];
#pragma unroll
  for (int mt = 0; mt < 2; mt++) {
    int r = wave * 32 + mt * 16 + (lane & 15);
#pragma unroll
    for (int ks = 0; ks < 2; ks++) {
      int cs = ks * 4 + (lane >> 4);  // 8-float chunk index (0..7)
      const float4 f0 = *(const float4*)&xg[r * 64 + (((2 * cs) ^ (r & 7)) << 2)];
      const float4 f1 = *(const float4*)&xg[r * 64 + (((2 * cs + 1) ^ (r & 7)) << 2)];
      bf8 v;
      v[0] = (short)f2bf(f0.x); v[1] = (short)f2bf(f0.y);
      v[2] = (short)f2bf(f0.z); v[3] = (short)f2bf(f0.w);
      v[4] = (short)f2bf(f1.x); v[5] = (short)f2bf(f1.y);
      v[6] = (short)f2bf(f1.z); v[7] = (short)f2bf(f1.w);
      afr[mt][ks] = v;
    }
  }

  // ---- skip GEMM (register-only + L2 B loads)
  f32x4 acc[2][8];
#pragma unroll
  for (int mt = 0; mt < 2; mt++)
#pragma unroll
    for (int nt = 0; nt < 8; nt++) { f32x4 z; z[0] = 0; z[1] = 0; z[2] = 0; z[3] = 0; acc[mt][nt] = z; }
#pragma unroll
  for (int ks = 0; ks < 2; ks++)
#pragma unroll
    for (int nt = 0; nt < 8; nt++) {
      int co = nt * 16 + (lane & 15);
      bf8 bbf = *(const bf8*)&swT[co * 64 + ks * 32 + (lane >> 4) * 8];
      acc[0][nt] = __builtin_amdgcn_mfma_f32_16x16x32_bf16(afr[0][ks], bbf, acc[0][nt], 0, 0, 0);
      acc[1][nt] = __builtin_amdgcn_mfma_f32_16x16x32_bf16(afr[1][ks], bbf, acc[1][nt], 0, 0, 0);
    }

  __syncthreads();  // all fragment reads done before reuse of xg
  for (int i = tid; i < 128 * 130; i += 256) xg[i] = 0.f;
  if (tid < 128) nrmsh[tid] = 0.f;
  bnred[tid] = 0.f;
  __syncthreads();

  // ---- gather map2token: points of tokens [lt0, lt0+128) are contiguous in listT
  const int h = tid >> 7, c = tid & 127;
  int pbeg = offT[(b << 12) + lt0];
  int pend = (lt0 == 4096 - 128) ? 4096 : offT[(b << 12) + lt0 + 128];
#pragma unroll 4
  for (int pi = pbeg + h; pi < pend; pi += 2) {
    int p = listT[(b << 12) + pi];
    int tok = idxagg[(b << 12) + p];
    int cell = cl32[(b << 12) + p];
    float v = aw[(b << 12) + p];
    float yv = y[(((size_t)(b << 10)) + cell) * 128 + c];
    atomicAdd(&xg[(tok - lt0) * 130 + c], yv * v);
    if (c == 0) atomicAdd(&nrmsh[tok - lt0], v);
  }
  __syncthreads();

  // ---- epilogue: combine, write XT once, accumulate BN sums
  float bs[8], bq[8];
#pragma unroll
  for (int nt = 0; nt < 8; nt++) { bs[nt] = 0.f; bq[nt] = 0.f; }
#pragma unroll
  for (int mt = 0; mt < 2; mt++)
#pragma unroll
    for (int nt = 0; nt < 8; nt++) {
      int co = nt * 16 + (lane & 15);
#pragma unroll
      for (int j = 0; j < 4; j++) {
        int r = wave * 32 + mt * 16 + (lane >> 4) * 4 + j;
        float val = acc[mt][nt][j] + xg[r * 130 + co] / (nrmsh[r] + EPSF);
        XT[((size_t)(t0 + r)) * 128 + co] = val;
        bs[nt] += val; bq[nt] += val * val;
      }
    }
#pragma unroll
  for (int nt = 0; nt < 8; nt++) {
    float s = bs[nt], q = bq[nt];
    s += __shfl_xor(s, 16, 64); s += __shfl_xor(s, 32, 64);
    q += __shfl_xor(q, 16, 64); q += __shfl_xor(q, 32, 64);
    if (lane < 16) {
      atomicAdd(&bnred[nt * 16 + lane], s);
      atomicAdd(&bnred[128 + nt * 16 + lane], q);
    }
  }
  __syncthreads();
  unsafeAtomicAdd(&BN[tid], bnred[tid]);
}

// ---------- K8: per-channel scale/shift ----------
__global__ void k_bnfin(const float* __restrict__ bn, const float* __restrict__ gamma,
                        const float* __restrict__ beta, float* __restrict__ ss) {
  int c = threadIdx.x;  // 128
  float n = (float)(BB * NN);
  float mean = bn[c] / n;
  float var = bn[128 + c] / n - mean * mean;
  float sc = gamma[c] * rsqrtf(var + BNEPS);
  ss[c] = sc;
  ss[128 + c] = beta[c] - mean * sc;
}

// ---------- K9: conf + weight ----------
__global__ __launch_bounds__(256) void k_conf(const float* __restrict__ XT, const float* __restrict__ ss,
                                              const float* __restrict__ confw, const float* __restrict__ confb,
                                              float* __restrict__ conf_out, float* __restrict__ wgt) {
  int gid = blockIdx.x * 256 + threadIdx.x;
  int p = gid >> 6, lane = gid & 63;
  const float* row = XT + (size_t)p * 128;
  float v0 = row[lane] * ss[lane] + ss[128 + lane];
  float v1 = row[64 + lane] * ss[64 + lane] + ss[192 + lane];
  float s = v0 * confw[lane] + v1 * confw[64 + lane];
#pragma unroll
  for (int off = 32; off; off >>= 1) s += __shfl_down(s, off, 64);
  if (lane == 0) {
    float cf = s + confb[0];
    conf_out[p] = cf;
    wgt[p] = __expf(cf);
  }
}

// ---------- K10: cluster as GATHER: one wave per 32x32 cell; write relu'd x_down once ----------
__global__ __launch_bounds__(256) void k_cluster(const float* __restrict__ XT, const float* __restrict__ ss,
                                                 const float* __restrict__ wgt, const int* __restrict__ idxagg,
                                                 const int* __restrict__ cnt32, const int* __restrict__ off32,
                                                 const int* __restrict__ list32,
                                                 float* __restrict__ xd, float* __restrict__ cnrm) {
  int blk = blockIdx.x;                       // 16384
  int sblk = (blk & 7) * 2048 + (blk >> 3);   // XCD swizzle
  int wid = sblk * 4 + (threadIdx.x >> 6);    // cell id in [0, 64*1024)
  int lane = threadIdx.x & 63;
  int b = wid >> 10;
  int n = cnt32[wid], o = off32[wid];
  float sc0 = ss[lane], sh0 = ss[128 + lane];
  float sc1 = ss[64 + lane], sh1 = ss[192 + lane];
  float s0 = 0.f, s1 = 0.f, sv = 0.f;
#pragma unroll 2
  for (int i = 0; i < n; i++) {
    int p = list32[(b << 12) + o + i];
    int idx = idxagg[(b << 12) + p];
    float v = wgt[(b << 12) + idx];
    const float* row = XT + ((size_t)((b << 12) + idx)) * 128;
    s0 += (row[lane] * sc0 + sh0) * v;
    s1 += (row[64 + lane] * sc1 + sh1) * v;
    sv += v;
  }
  float inv = 1.f / (sv + EPSF);
  size_t ro = (size_t)wid * 128;
  xd[ro + lane]      = fmaxf(s0 * inv, 0.f);
  xd[ro + 64 + lane] = fmaxf(s1 * inv, 0.f);
  if (lane == 0) cnrm[wid] = sv;
}

// ---------- K11: agg_weight_down (pre-norm) + per-batch max ----------
__global__ __launch_bounds__(256) void k_awd(const float* __restrict__ wgt, const float* __restrict__ aw,
                                             const int* __restrict__ idxagg, const int* __restrict__ cell32,
                                             const float* __restrict__ cnrm,
                                             float* __restrict__ awd, int* __restrict__ maxb) {
  int p = blockIdx.x * 256 + threadIdx.x;  // B*N
  int b = p >> 12;
  float v = wgt[(b << 12) + idxagg[p]];
  float wt = v / (cnrm[(b << 10) + cell32[p]] + EPSF);
  float a = aw[p] * wt;
  awd[p] = a;
  float m = a;
#pragma unroll
  for (int off = 32; off; off >>= 1) m = fmaxf(m, __shfl_down(m, off, 64));
  if ((threadIdx.x & 63) == 0) atomicMax(&maxb[b], __float_as_int(m));  // all values > 0
}

// ---------- K12: normalize awd ----------
__global__ __launch_bounds__(256) void k_awdnorm(float* __restrict__ awd, const int* __restrict__ maxb) {
  int p = blockIdx.x * 256 + threadIdx.x;
  int b = p >> 12;
  awd[p] = awd[p] / __int_as_float(maxb[b]);
}

// ---------- K13: x_act = relu(xt*scale+shift) in place ----------
__global__ __launch_bounds__(256) void k_xact(float* __restrict__ XT, const float* __restrict__ ss) {
  int i4 = blockIdx.x * 256 + threadIdx.x;  // 8,388,608
  int c0 = (i4 & 31) * 4;
  float4 v = *(float4*)&XT[(size_t)i4 * 4];
  const float4 sc = *(const float4*)&ss[c0];
  const float4 sh = *(const float4*)&ss[128 + c0];
  v.x = fmaxf(v.x * sc.x + sh.x, 0.f);
  v.y = fmaxf(v.y * sc.y + sh.y, 0.f);
  v.z = fmaxf(v.z * sc.z + sh.z, 0.f);
  v.w = fmaxf(v.w * sc.w + sh.w, 0.f);
  *(float4*)&XT[(size_t)i4 * 4] = v;
}

extern "C" void kernel_launch(void* const* d_in, const int* in_sizes, int n_in,
                              void* d_out, int out_size, void* d_ws, size_t ws_size,
                              hipStream_t stream) {
  (void)in_sizes; (void)n_in; (void)out_size;
  const float* x      = (const float*)d_in[0];
  const float* loc    = (const float*)d_in[1];
  const int*   idxagg = (const int*)  d_in[2];
  const float* aw     = (const float*)d_in[3];
  const float* convw  = (const float*)d_in[4];
  const float* convb  = (const float*)d_in[5];
  const float* skipw  = (const float*)d_in[6];
  const float* gamma  = (const float*)d_in[7];
  const float* beta   = (const float*)d_in[8];
  const float* confw  = (const float*)d_in[9];
  const float* confb  = (const float*)d_in[10];

  char* ws = (char*)d_ws;
  float*    Y     = (float*)(ws + 0);           // 33,554,432
  ushort_t* XMB   = (ushort_t*)(ws + 33554432); // 35,684,352 (padded 66x66 bf16 map)
  ushort_t* WT    = (ushort_t*)(ws + 69238784); // 147,456
  ushort_t* SWT   = (ushort_t*)(ws + 69386240); // 16,384
  float*    WGT   = (float*)(ws + 69402624);    // 1,048,576
  int*      CL64  = (int*)  (ws + 70451200);    // 1,048,576
  int*      CL32  = (int*)  (ws + 71499776);    // 1,048,576
  float*    CNRM  = (float*)(ws + 72548352);    // 262,144
  float*    BN    = (float*)(ws + 72810496);    // 1,024
  float*    SS    = (float*)(ws + 72811520);    // 1,024
  int*      MAXB  = (int*)  (ws + 72812544);    // 256
  int*      CNT64 = (int*)  (ws + 72812800);    // 1,048,576
  int*      OFF64 = (int*)  (ws + 73861376);    // 1,048,576
  int*      CUR64 = (int*)  (ws + 74909952);    // 1,048,576
  int*      CNTT  = (int*)  (ws + 75958528);    // 1,048,576
  int*      OFFT  = (int*)  (ws + 77007104);    // 1,048,576
  int*      CURT  = (int*)  (ws + 78055680);    // 1,048,576
  int*      CNT32 = (int*)  (ws + 79104256);    // 262,144
  int*      OFF32 = (int*)  (ws + 79366400);    // 262,144
  int*      CUR32 = (int*)  (ws + 79628544);    // 262,144
  int*      LIST64= (int*)  (ws + 79890688);    // 1,048,576
  int*      LISTT = (int*)  (ws + 80939264);    // 1,048,576
  int*      LIST32= (int*)  (ws + 81987840);    // 1,048,576
  if (ws_size < 83036416) return;  // insufficient workspace -> visible failure

  float* out    = (float*)d_out;
  float* O_XD   = out;               // x_down: 8,388,608 floats
  float* O_IDX  = out + 8388608;     // idx_agg_down (as float): 262,144
  float* O_AWD  = out + 8650752;     // agg_weight_down: 262,144
  float* XT     = out + 8912896;     // x_act region; holds xt pre-BN until k_xact
  float* O_CONF = out + 42467328;    // conf: 262,144

  hipMemsetAsync(XMB, 0, 35684352, stream);   // borders (interior overwritten)
  hipMemsetAsync(BN, 0, 1024, stream);
  hipMemsetAsync(MAXB, 0, 256, stream);
  hipMemsetAsync(CNT64, 0, 1048576, stream);
  hipMemsetAsync(CNTT, 0, 1048576, stream);
  hipMemsetAsync(CNT32, 0, 262144, stream);

  k_prep   <<<1024,  256, 0, stream>>>(loc, idxagg, CL64, CL32, O_IDX, CNT64, CNT32, CNTT);
  k_wprep  <<<320,   256, 0, stream>>>(convw, skipw, WT, SWT);
  k_scan   <<<64,    256, 0, stream>>>(CNT64, OFF64, CUR64, CNTT, OFFT, CURT, CNT32, OFF32, CUR32);
  k_fill   <<<1024,  256, 0, stream>>>(idxagg, CL64, CL32, CUR64, CURT, CUR32, LIST64, LISTT, LIST32);
  k_t2m    <<<65536, 256, 0, stream>>>(x, idxagg, CNT64, OFF64, LIST64, XMB);
  k_conv   <<<512,   256, 0, stream>>>(XMB, WT, convb, Y);
  k_xt     <<<2048,  256, 0, stream>>>(x, SWT, Y, aw, idxagg, CL32, OFFT, LISTT, XT, BN);
  k_bnfin  <<<1,     128, 0, stream>>>(BN, gamma, beta, SS);
  k_conf   <<<65536, 256, 0, stream>>>(XT, SS, confw, confb, O_CONF, WGT);
  k_cluster<<<16384, 256, 0, stream>>>(XT, SS, WGT, idxagg, CNT32, OFF32, LIST32, O_XD, CNRM);
  k_awd    <<<1024,  256, 0, stream>>>(WGT, aw, idxagg, CL32, CNRM, O_AWD, MAXB);
  k_awdnorm<<<1024,  256, 0, stream>>>(O_AWD, MAXB);
  k_xact   <<<32768, 256, 0, stream>>>(XT, SS);
}

// Round 3
// 446.538 us; speedup vs baseline: 1.6082x; 1.3504x over previous
//
#include <hip/hip_runtime.h>

// Problem constants (setup_inputs: B=64, N=4096, C=64, Cout=128, H=W=64)
#define BB 64
#define NN 4096
#define CCH 64
#define CO 128
#define HH 64
#define WW 64
#define H2 32
#define W2 32
#define EPSF 1e-6f
#define BNEPS 1e-5f

typedef unsigned short ushort_t;
using bf8  = __attribute__((ext_vector_type(8))) short;   // 8 bf16 (4 VGPRs)
using f32x4 = __attribute__((ext_vector_type(4))) float;  // MFMA accumulator

__device__ inline ushort_t f2bf(float f) {
  unsigned u = __float_as_uint(f);
  unsigned r = (u + 0x7fffu + ((u >> 16) & 1u)) >> 16;  // RNE
  return (ushort_t)r;
}

__device__ inline void gload_lds16(const void* src, void* ldsdst) {
  __builtin_amdgcn_global_load_lds((const __attribute__((address_space(1))) void*)src,
                                   (__attribute__((address_space(3))) void*)ldsdst, 16, 0, 0);
}

// ---------- K1: point cells + idx_agg_down output + count phase of 3 sorts ----------
__global__ __launch_bounds__(256) void k_prep(const float* __restrict__ loc, const int* __restrict__ idxagg,
                                              int* __restrict__ cell64, int* __restrict__ cell32,
                                              float* __restrict__ idx_out,
                                              int* __restrict__ cnt64, int* __restrict__ cnt32,
                                              int* __restrict__ cntT) {
  int i = blockIdx.x * 256 + threadIdx.x;  // exactly B*N = 262144
  int b = i >> 12;
  float lx = loc[2 * i], ly = loc[2 * i + 1];
  lx = fminf(fmaxf(lx, -1.f), 1.f) * 0.5f + 0.5f;
  ly = fminf(fmaxf(ly, -1.f), 1.f) * 0.5f + 0.5f;
  int cx = (int)fminf(fmaxf(rintf(lx * (WW - 1)), 0.f), (float)(WW - 1));
  int cy = (int)fminf(fmaxf(rintf(ly * (HH - 1)), 0.f), (float)(HH - 1));
  int c64 = cx + cy * WW;
  cell64[i] = c64;
  int cx2 = (int)fminf(fmaxf(rintf(lx * (W2 - 1)), 0.f), (float)(W2 - 1));
  int cy2 = (int)fminf(fmaxf(rintf(ly * (H2 - 1)), 0.f), (float)(H2 - 1));
  int c2 = cx2 + cy2 * W2;
  cell32[i] = c2;
  idx_out[i] = (float)c2;
  atomicAdd(&cnt64[(b << 12) + c64], 1);
  atomicAdd(&cnt32[(b << 10) + c2], 1);
  atomicAdd(&cntT[(b << 12) + idxagg[i]], 1);
}

// ---------- K2: bf16 transposed weights ----------
__global__ __launch_bounds__(256) void k_wprep(const float* __restrict__ convw, const float* __restrict__ skipw,
                                               ushort_t* __restrict__ wT, ushort_t* __restrict__ swT) {
  int e = blockIdx.x * 256 + threadIdx.x;  // 9*64*128 + 64*128 = 81920
  if (e < 9 * CCH * CO) {
    int co = e & 127, k = e >> 7;
    wT[co * 576 + k] = f2bf(convw[k * CO + co]);
  } else {
    int e2 = e - 9 * CCH * CO;
    int co = e2 & 127, k = e2 >> 7;
    swT[co * 64 + k] = f2bf(skipw[k * CO + co]);
  }
}

// ---------- scan helper: exclusive prefix over L (multiple of 256) ints, 256 threads ----------
__device__ void block_exscan(const int* __restrict__ in, int* __restrict__ out, int* __restrict__ cur, int L) {
  __shared__ int partial[256];
  int tid = threadIdx.x;
  int per = L >> 8;
  int base = tid * per;
  int s = 0;
  for (int i = 0; i < per; i++) s += in[base + i];
  __syncthreads();  // protect partial[] from previous call
  partial[tid] = s;
  __syncthreads();
  for (int d = 1; d < 256; d <<= 1) {
    int v = (tid >= d) ? partial[tid - d] : 0;
    __syncthreads();
    partial[tid] += v;
    __syncthreads();
  }
  int run = (tid == 0) ? 0 : partial[tid - 1];
  for (int i = 0; i < per; i++) {
    out[base + i] = run;
    cur[base + i] = run;
    run += in[base + i];
  }
}

// ---------- K3: per-batch prefix scans ----------
__global__ __launch_bounds__(256) void k_scan(const int* __restrict__ cnt64, int* __restrict__ off64, int* __restrict__ cur64,
                                              const int* __restrict__ cntT, int* __restrict__ offT, int* __restrict__ curT,
                                              const int* __restrict__ cnt32, int* __restrict__ off32, int* __restrict__ cur32) {
  int b = blockIdx.x;  // 64
  block_exscan(cnt64 + ((size_t)b << 12), off64 + ((size_t)b << 12), cur64 + ((size_t)b << 12), 4096);
  block_exscan(cntT + ((size_t)b << 12), offT + ((size_t)b << 12), curT + ((size_t)b << 12), 4096);
  block_exscan(cnt32 + ((size_t)b << 10), off32 + ((size_t)b << 10), cur32 + ((size_t)b << 10), 1024);
}

// ---------- K4: fill sorted PACKED lists (payload resolved at fill time) ----------
__global__ __launch_bounds__(256) void k_fill(const int* __restrict__ idxagg, const int* __restrict__ cl64,
                                              const int* __restrict__ cl32, const float* __restrict__ aw,
                                              int* __restrict__ cur64, int* __restrict__ curT, int* __restrict__ cur32,
                                              int* __restrict__ list64i, uint2* __restrict__ listT2,
                                              int* __restrict__ list32i) {
  int i = blockIdx.x * 256 + threadIdx.x;  // B*N
  int b = i >> 12;
  int idx = idxagg[i];
  int c64 = cl64[i], c32 = cl32[i];
  int pos = atomicAdd(&cur64[(b << 12) + c64], 1);
  list64i[(b << 12) + pos] = idx;                     // token index (what t2m needs)
  pos = atomicAdd(&curT[(b << 12) + idx], 1);
  uint2 rec; rec.x = (unsigned)c32; rec.y = __float_as_uint(aw[i]);
  listT2[(b << 12) + pos] = rec;                      // {cell, agg_weight}
  pos = atomicAdd(&cur32[(b << 10) + c32], 1);
  list32i[(b << 12) + pos] = idx;                     // token index (what cluster needs)
}

// ---------- K5: token2map as GATHER (one wave per 64x64 cell), unroll-4 prefetch ----------
__global__ __launch_bounds__(256) void k_t2m(const float* __restrict__ x,
                                             const int* __restrict__ cnt64, const int* __restrict__ off64,
                                             const int* __restrict__ list64i, ushort_t* __restrict__ xmb) {
  int blk = blockIdx.x;                       // 65536
  int sblk = (blk & 7) * 8192 + (blk >> 3);   // XCD swizzle: batch-contiguous per XCD
  int g = sblk * 4 + (threadIdx.x >> 6);      // cell id in [0, 64*4096)
  int lane = threadIdx.x & 63;
  int b = g >> 12, cell = g & 4095;
  int n = cnt64[g], o = off64[g];
  const int* lp = list64i + ((size_t)b << 12) + o;
  const float* xb = x + ((size_t)b << 18);
  float s0 = 0.f, s1 = 0.f, s2 = 0.f, s3 = 0.f;
  int i = 0;
  for (; i + 4 <= n; i += 4) {
    int i0 = lp[i], i1 = lp[i + 1], i2 = lp[i + 2], i3 = lp[i + 3];
    s0 += xb[(size_t)i0 * 64 + lane];
    s1 += xb[(size_t)i1 * 64 + lane];
    s2 += xb[(size_t)i2 * 64 + lane];
    s3 += xb[(size_t)i3 * 64 + lane];
  }
  for (; i < n; i++) s0 += xb[(size_t)lp[i] * 64 + lane];
  float avg = (s0 + s1 + s2 + s3) / ((float)n + EPSF);
  int r = cell >> 6, cc = cell & 63;
  xmb[(((size_t)(b * 66 + r + 1)) * 66 + cc + 1) * 64 + lane] = f2bf(avg);
}

// ---------- K6: conv 3x3 stride2 pad1 implicit GEMM (unchanged, verified round 1) ----------
__global__ __launch_bounds__(256) void k_conv(const ushort_t* __restrict__ xmb, const ushort_t* __restrict__ wT,
                                              const float* __restrict__ cb, float* __restrict__ y) {
  __shared__ ushort_t A[2][4096];
  const int tid = threadIdx.x;
  const int wave = tid >> 6, lane = tid & 63;
  const int m0 = blockIdx.x * 128;

  f32x4 acc[2][8];
  {
    float bv[8];
#pragma unroll
    for (int nt = 0; nt < 8; nt++) bv[nt] = cb[nt * 16 + (lane & 15)];
#pragma unroll
    for (int mt = 0; mt < 2; mt++)
#pragma unroll
      for (int nt = 0; nt < 8; nt++) {
        f32x4 a; a[0] = bv[nt]; a[1] = bv[nt]; a[2] = bv[nt]; a[3] = bv[nt];
        acc[mt][nt] = a;
      }
  }

  const int srcslot = (((lane & 3) ^ ((lane >> 3) & 3))) * 8;
  int sb[2], soy[2], sox[2];
#pragma unroll
  for (int q = 0; q < 2; q++) {
    int r = wave * 32 + q * 16 + (lane >> 2);
    int s = m0 + r;
    sb[q] = s >> 10; soy[q] = (s >> 5) & 31; sox[q] = s & 31;
  }

  auto stage = [&](int ks, int buf) {
    int kp = ks >> 1, ci0 = (ks & 1) * 32;
    int ky = kp / 3, kx = kp - ky * 3;
#pragma unroll
    for (int q = 0; q < 2; q++) {
      int iy = 2 * soy[q] + ky, ix = 2 * sox[q] + kx;
      const ushort_t* src = xmb + (((size_t)sb[q] * 66 + iy) * 66 + ix) * 64 + ci0 + srcslot;
      gload_lds16(src, &A[buf][(wave * 32 + q * 16) * 32]);
    }
  };

  stage(0, 0);
  const int rdslotx = (lane >> 1) & 3;
  for (int ks = 0; ks < 18; ks++) {
    int buf = ks & 1;
    __syncthreads();
    if (ks < 17) stage(ks + 1, buf ^ 1);
    bf8 a[2];
#pragma unroll
    for (int mt = 0; mt < 2; mt++) {
      int r = wave * 32 + mt * 16 + (lane & 15);
      int slot = (lane >> 4) ^ rdslotx;
      a[mt] = *(const bf8*)&A[buf][r * 32 + slot * 8];
    }
    int k0 = ks * 32 + (lane >> 4) * 8;
#pragma unroll
    for (int nt = 0; nt < 8; nt++) {
      int co = nt * 16 + (lane & 15);
      bf8 bbf = *(const bf8*)&wT[co * 576 + k0];
      acc[0][nt] = __builtin_amdgcn_mfma_f32_16x16x32_bf16(a[0], bbf, acc[0][nt], 0, 0, 0);
      acc[1][nt] = __builtin_amdgcn_mfma_f32_16x16x32_bf16(a[1], bbf, acc[1][nt], 0, 0, 0);
    }
  }
#pragma unroll
  for (int mt = 0; mt < 2; mt++)
#pragma unroll
    for (int nt = 0; nt < 8; nt++) {
      int co = nt * 16 + (lane & 15);
#pragma unroll
      for (int j = 0; j < 4; j++) {
        int srow = m0 + wave * 32 + mt * 16 + (lane >> 4) * 4 + j;
        y[(size_t)srow * 128 + co] = acc[mt][nt][j];
      }
    }
}

// ---------- K7: FUSED xt = gather_m2t(y)/norm + x@skip_w + BN partials ----------
// 64-token tile, 4096 blocks. Wave-per-token register gather (no LDS atomics).
__global__ __launch_bounds__(256) void k_xt(const float* __restrict__ x, const ushort_t* __restrict__ swT,
                                            const float* __restrict__ y,
                                            const uint2* __restrict__ listT2, const int* __restrict__ offT,
                                            float* __restrict__ XT, float* __restrict__ BNP) {
  __shared__ float xg[64 * 132];   // 33792 B; bytes [0,16384) double as f32 x staging
  __shared__ float nrmsh[64];
  __shared__ float bnred[256];
  const int tid = threadIdx.x, wave = tid >> 6, lane = tid & 63;
  int blk = blockIdx.x;                       // 4096
  int sblk = (blk & 7) * 512 + (blk >> 3);    // XCD swizzle (8 batches per XCD)
  const int t0 = sblk * 64;
  const int b = t0 >> 12, lt0 = t0 & 4095;

  // ---- stage x tile: 64 rows x 64 f32 = 16KB; 16 chunks of 1KB (4 rows each), swizzled slots
#pragma unroll
  for (int q = 0; q < 4; q++) {
    int ch = wave * 4 + q;
    int r = ch * 4 + (lane >> 4);
    int sp = lane & 15;
    const float* src = x + ((size_t)(t0 + r)) * 64 + ((sp ^ (r & 7)) << 2);
    gload_lds16(src, (char*)xg + ch * 1024);
  }
  __syncthreads();

  // ---- A fragments (f32 -> bf16) ----
  bf8 afr[2];
  {
    int r = wave * 16 + (lane & 15);
#pragma unroll
    for (int ks = 0; ks < 2; ks++) {
      int cs = ks * 4 + (lane >> 4);
      const float4 f0 = *(const float4*)&xg[r * 64 + (((2 * cs) ^ (r & 7)) << 2)];
      const float4 f1 = *(const float4*)&xg[r * 64 + (((2 * cs + 1) ^ (r & 7)) << 2)];
      bf8 v;
      v[0] = (short)f2bf(f0.x); v[1] = (short)f2bf(f0.y);
      v[2] = (short)f2bf(f0.z); v[3] = (short)f2bf(f0.w);
      v[4] = (short)f2bf(f1.x); v[5] = (short)f2bf(f1.y);
      v[6] = (short)f2bf(f1.z); v[7] = (short)f2bf(f1.w);
      afr[ks] = v;
    }
  }

  // ---- skip GEMM: wave computes rows [wave*16, wave*16+16) x 128 cols
  f32x4 acc[8];
#pragma unroll
  for (int nt = 0; nt < 8; nt++) { f32x4 z; z[0] = 0; z[1] = 0; z[2] = 0; z[3] = 0; acc[nt] = z; }
#pragma unroll
  for (int ks = 0; ks < 2; ks++)
#pragma unroll
    for (int nt = 0; nt < 8; nt++) {
      int co = nt * 16 + (lane & 15);
      bf8 bbf = *(const bf8*)&swT[co * 64 + ks * 32 + (lane >> 4) * 8];
      acc[nt] = __builtin_amdgcn_mfma_f32_16x16x32_bf16(afr[ks], bbf, acc[nt], 0, 0, 0);
    }

  bnred[tid] = 0.f;
  __syncthreads();  // fragment reads done; xg reusable for gather results

  // ---- m2t gather: wave-per-token, register accumulate, single ds_write
  {
    int myoff = 0;
    if (lane <= 16) {
      int gtok = lt0 + wave * 16 + lane;
      myoff = (gtok >= 4096) ? 4096 : offT[(b << 12) + gtok];
    }
    const uint2* ltb = listT2 + ((size_t)b << 12);
    const float* yb = y + ((size_t)b << 17);  // b*1024*128
#pragma unroll 1
    for (int rr = 0; rr < 16; rr++) {
      int pbeg = __shfl(myoff, rr, 64);
      int pend = __shfl(myoff, rr + 1, 64);
      float sx = 0.f, sy = 0.f, vs = 0.f;
      for (int pi = pbeg; pi < pend; pi++) {
        uint2 rec = ltb[pi];
        float v = __uint_as_float(rec.y);
        const float2 yv = *(const float2*)&yb[(size_t)rec.x * 128 + lane * 2];
        sx += yv.x * v; sy += yv.y * v; vs += v;
      }
      int r = wave * 16 + rr;
      float2 o; o.x = sx; o.y = sy;
      *(float2*)&xg[r * 132 + lane * 2] = o;
      if (lane == 0) nrmsh[r] = vs;
    }
  }
  __syncthreads();

  // ---- epilogue: combine, write XT once, BN partial sums
#pragma unroll
  for (int nt = 0; nt < 8; nt++) {
    int co = nt * 16 + (lane & 15);
    float s = 0.f, q = 0.f;
#pragma unroll
    for (int j = 0; j < 4; j++) {
      int r = wave * 16 + (lane >> 4) * 4 + j;
      float val = acc[nt][j] + xg[r * 132 + co] / (nrmsh[r] + EPSF);
      XT[((size_t)(t0 + r)) * 128 + co] = val;
      s += val; q += val * val;
    }
    s += __shfl_xor(s, 16, 64); s += __shfl_xor(s, 32, 64);
    q += __shfl_xor(q, 16, 64); q += __shfl_xor(q, 32, 64);
    if (lane < 16) {
      atomicAdd(&bnred[nt * 16 + lane], s);
      atomicAdd(&bnred[128 + nt * 16 + lane], q);
    }
  }
  __syncthreads();
  unsafeAtomicAdd(&BNP[(blk & 63) * 256 + tid], bnred[tid]);
}

// ---------- K8: reduce BN partials -> per-channel scale/shift ----------
__global__ void k_bnfin(const float* __restrict__ BNP, const float* __restrict__ gamma,
                        const float* __restrict__ beta, float* __restrict__ ss) {
  int c = threadIdx.x;  // 128
  float s = 0.f, q = 0.f;
#pragma unroll 4
  for (int k = 0; k < 64; k++) {
    s += BNP[k * 256 + c];
    q += BNP[k * 256 + 128 + c];
  }
  float n = (float)(BB * NN);
  float mean = s / n;
  float var = q / n - mean * mean;
  float sc = gamma[c] * rsqrtf(var + BNEPS);
  ss[c] = sc;
  ss[128 + c] = beta[c] - mean * sc;
}

// ---------- K9: conf + weight (+ optional fused x_act write) ----------
__global__ __launch_bounds__(256) void k_conf(const float* __restrict__ XT, const float* __restrict__ ss,
                                              const float* __restrict__ confw, const float* __restrict__ confb,
                                              float* __restrict__ conf_out, float* __restrict__ wgt,
                                              float* __restrict__ xa) {
  int gid = blockIdx.x * 256 + threadIdx.x;
  int p = gid >> 6, lane = gid & 63;
  const float* row = XT + (size_t)p * 128;
  float v0 = row[lane] * ss[lane] + ss[128 + lane];
  float v1 = row[64 + lane] * ss[64 + lane] + ss[192 + lane];
  if (xa) {
    xa[(size_t)p * 128 + lane] = fmaxf(v0, 0.f);
    xa[(size_t)p * 128 + 64 + lane] = fmaxf(v1, 0.f);
  }
  float s = v0 * confw[lane] + v1 * confw[64 + lane];
#pragma unroll
  for (int off = 32; off; off >>= 1) s += __shfl_down(s, off, 64);
  if (lane == 0) {
    float cf = s + confb[0];
    conf_out[p] = cf;
    wgt[p] = __expf(cf);
  }
}

// ---------- K10: cluster as GATHER (wave per 32x32 cell), idx-packed list, unroll-2 ----------
__global__ __launch_bounds__(256) void k_cluster(const float* __restrict__ XT, const float* __restrict__ ss,
                                                 const float* __restrict__ wgt,
                                                 const int* __restrict__ cnt32, const int* __restrict__ off32,
                                                 const int* __restrict__ list32i,
                                                 float* __restrict__ xd, float* __restrict__ cnrm) {
  int blk = blockIdx.x;                       // 16384
  int sblk = (blk & 7) * 2048 + (blk >> 3);   // XCD swizzle
  int wid = sblk * 4 + (threadIdx.x >> 6);
  int lane = threadIdx.x & 63;
  int b = wid >> 10;
  int n = cnt32[wid], o = off32[wid];
  const int* lp = list32i + ((size_t)b << 12) + o;
  const float* wb = wgt + ((size_t)b << 12);
  const float* xtb = XT + ((size_t)b << 19);  // b*4096*128
  float sc0 = ss[lane], sh0 = ss[128 + lane];
  float sc1 = ss[64 + lane], sh1 = ss[192 + lane];
  float s0 = 0.f, s1 = 0.f, sv = 0.f;
  int i = 0;
  for (; i + 2 <= n; i += 2) {
    int i0 = lp[i], i1 = lp[i + 1];
    float v0 = wb[i0], v1 = wb[i1];
    const float* r0 = xtb + (size_t)i0 * 128;
    const float* r1 = xtb + (size_t)i1 * 128;
    s0 += (r0[lane] * sc0 + sh0) * v0 + (r1[lane] * sc0 + sh0) * v1;
    s1 += (r0[64 + lane] * sc1 + sh1) * v0 + (r1[64 + lane] * sc1 + sh1) * v1;
    sv += v0 + v1;
  }
  if (i < n) {
    int i0 = lp[i];
    float v0 = wb[i0];
    const float* r0 = xtb + (size_t)i0 * 128;
    s0 += (r0[lane] * sc0 + sh0) * v0;
    s1 += (r0[64 + lane] * sc1 + sh1) * v0;
    sv += v0;
  }
  float inv = 1.f / (sv + EPSF);
  size_t ro = (size_t)wid * 128;
  xd[ro + lane]      = fmaxf(s0 * inv, 0.f);
  xd[ro + 64 + lane] = fmaxf(s1 * inv, 0.f);
  if (lane == 0) cnrm[wid] = sv;
}

// ---------- K11: agg_weight_down (pre-norm) + per-batch max ----------
__global__ __launch_bounds__(256) void k_awd(const float* __restrict__ wgt, const float* __restrict__ aw,
                                             const int* __restrict__ idxagg, const int* __restrict__ cell32,
                                             const float* __restrict__ cnrm,
                                             float* __restrict__ awd, int* __restrict__ maxb) {
  int p = blockIdx.x * 256 + threadIdx.x;  // B*N
  int b = p >> 12;
  float v = wgt[(b << 12) + idxagg[p]];
  float wt = v / (cnrm[(b << 10) + cell32[p]] + EPSF);
  float a = aw[p] * wt;
  awd[p] = a;
  float m = a;
#pragma unroll
  for (int off = 32; off; off >>= 1) m = fmaxf(m, __shfl_down(m, off, 64));
  if ((threadIdx.x & 63) == 0) atomicMax(&maxb[b], __float_as_int(m));  // all values > 0
}

// ---------- K12: normalize awd ----------
__global__ __launch_bounds__(256) void k_awdnorm(float* __restrict__ awd, const int* __restrict__ maxb) {
  int p = blockIdx.x * 256 + threadIdx.x;
  int b = p >> 12;
  awd[p] = awd[p] / __int_as_float(maxb[b]);
}

// ---------- K13 (fallback path only): x_act = relu(xt*scale+shift) in place ----------
__global__ __launch_bounds__(256) void k_xact(float* __restrict__ XT, const float* __restrict__ ss) {
  int i4 = blockIdx.x * 256 + threadIdx.x;  // 8,388,608
  int c0 = (i4 & 31) * 4;
  float4 v = *(float4*)&XT[(size_t)i4 * 4];
  const float4 sc = *(const float4*)&ss[c0];
  const float4 sh = *(const float4*)&ss[128 + c0];
  v.x = fmaxf(v.x * sc.x + sh.x, 0.f);
  v.y = fmaxf(v.y * sc.y + sh.y, 0.f);
  v.z = fmaxf(v.z * sc.z + sh.z, 0.f);
  v.w = fmaxf(v.w * sc.w + sh.w, 0.f);
  *(float4*)&XT[(size_t)i4 * 4] = v;
}

extern "C" void kernel_launch(void* const* d_in, const int* in_sizes, int n_in,
                              void* d_out, int out_size, void* d_ws, size_t ws_size,
                              hipStream_t stream) {
  (void)in_sizes; (void)n_in; (void)out_size;
  const float* x      = (const float*)d_in[0];
  const float* loc    = (const float*)d_in[1];
  const int*   idxagg = (const int*)  d_in[2];
  const float* aw     = (const float*)d_in[3];
  const float* convw  = (const float*)d_in[4];
  const float* convb  = (const float*)d_in[5];
  const float* skipw  = (const float*)d_in[6];
  const float* gamma  = (const float*)d_in[7];
  const float* beta   = (const float*)d_in[8];
  const float* confw  = (const float*)d_in[9];
  const float* confb  = (const float*)d_in[10];

  char* ws = (char*)d_ws;
  float*    Y     = (float*)(ws + 0);           // 33,554,432
  ushort_t* XMB   = (ushort_t*)(ws + 33554432); // 35,684,352 (padded 66x66 bf16 map)
  ushort_t* WT    = (ushort_t*)(ws + 69238784); // 147,456
  ushort_t* SWT   = (ushort_t*)(ws + 69386240); // 16,384
  float*    WGT   = (float*)(ws + 69402624);    // 1,048,576
  int*      CL64  = (int*)  (ws + 70451200);    // 1,048,576
  int*      CL32  = (int*)  (ws + 71499776);    // 1,048,576
  float*    CNRM  = (float*)(ws + 72548352);    // 262,144
  float*    SS    = (float*)(ws + 72810496);    // 1,024
  int*      MAXB  = (int*)  (ws + 72811520);    // 256
  float*    BNP   = (float*)(ws + 72811776);    // 65,536 (64 slots x 256)
  int*      CNT64 = (int*)  (ws + 72877312);    // 1,048,576
  int*      OFF64 = (int*)  (ws + 73925888);    // 1,048,576
  int*      CUR64 = (int*)  (ws + 74974464);    // 1,048,576
  int*      CNTT  = (int*)  (ws + 76023040);    // 1,048,576
  int*      OFFT  = (int*)  (ws + 77071616);    // 1,048,576
  int*      CURT  = (int*)  (ws + 78120192);    // 1,048,576
  int*      CNT32 = (int*)  (ws + 79168768);    // 262,144
  int*      OFF32 = (int*)  (ws + 79430912);    // 262,144
  int*      CUR32 = (int*)  (ws + 79693056);    // 262,144
  int*      LIST64= (int*)  (ws + 79955200);    // 1,048,576 (token idx)
  uint2*    LISTT2= (uint2*)(ws + 81003776);    // 2,097,152 ({cell, aw})
  int*      LIST32= (int*)  (ws + 83100928);    // 1,048,576 (token idx)
  const size_t BASE_END = 84149504;
  if (ws_size < BASE_END) return;  // insufficient workspace -> visible failure
  const bool big = ws_size >= BASE_END + 134217728ull;

  float* out    = (float*)d_out;
  float* O_XD   = out;               // x_down: 8,388,608 floats
  float* O_IDX  = out + 8388608;     // idx_agg_down (as float): 262,144
  float* O_AWD  = out + 8650752;     // agg_weight_down: 262,144
  float* XA     = out + 8912896;     // x_act: 33,554,432 floats
  float* O_CONF = out + 42467328;    // conf: 262,144
  float* XT     = big ? (float*)(ws + BASE_END) : XA;  // pre-BN xt

  hipMemsetAsync(XMB, 0, 35684352, stream);   // borders (interior overwritten)
  hipMemsetAsync(BNP, 0, 65536, stream);
  hipMemsetAsync(MAXB, 0, 256, stream);
  hipMemsetAsync(CNT64, 0, 1048576, stream);
  hipMemsetAsync(CNTT, 0, 1048576, stream);
  hipMemsetAsync(CNT32, 0, 262144, stream);

  k_prep   <<<1024,  256, 0, stream>>>(loc, idxagg, CL64, CL32, O_IDX, CNT64, CNT32, CNTT);
  k_wprep  <<<320,   256, 0, stream>>>(convw, skipw, WT, SWT);
  k_scan   <<<64,    256, 0, stream>>>(CNT64, OFF64, CUR64, CNTT, OFFT, CURT, CNT32, OFF32, CUR32);
  k_fill   <<<1024,  256, 0, stream>>>(idxagg, CL64, CL32, aw, CUR64, CURT, CUR32, LIST64, LISTT2, LIST32);
  k_t2m    <<<65536, 256, 0, stream>>>(x, CNT64, OFF64, LIST64, XMB);
  k_conv   <<<512,   256, 0, stream>>>(XMB, WT, convb, Y);
  k_xt     <<<4096,  256, 0, stream>>>(x, SWT, Y, LISTT2, OFFT, XT, BNP);
  k_bnfin  <<<1,     128, 0, stream>>>(BNP, gamma, beta, SS);
  k_conf   <<<65536, 256, 0, stream>>>(XT, SS, confw, confb, O_CONF, WGT, big ? XA : nullptr);
  k_cluster<<<16384, 256, 0, stream>>>(XT, SS, WGT, CNT32, OFF32, LIST32, O_XD, CNRM);
  k_awd    <<<1024,  256, 0, stream>>>(WGT, aw, idxagg, CL32, CNRM, O_AWD, MAXB);
  k_awdnorm<<<1024,  256, 0, stream>>>(O_AWD, MAXB);
  if (!big) k_xact<<<32768, 256, 0, stream>>>(XT, SS);
}

// Round 4
// 389.249 us; speedup vs baseline: 1.8448x; 1.1472x over previous
//
#include <hip/hip_runtime.h>

// Problem constants (setup_inputs: B=64, N=4096, C=64, Cout=128, H=W=64)
#define BB 64
#define NN 4096
#define CCH 64
#define CO 128
#define HH 64
#define WW 64
#define H2 32
#define W2 32
#define EPSF 1e-6f
#define BNEPS 1e-5f

typedef unsigned short ushort_t;
using bf8  = __attribute__((ext_vector_type(8))) short;   // 8 bf16 (4 VGPRs)
using f32x4 = __attribute__((ext_vector_type(4))) float;  // MFMA accumulator

__device__ inline ushort_t f2bf(float f) {
  unsigned u = __float_as_uint(f);
  unsigned r = (u + 0x7fffu + ((u >> 16) & 1u)) >> 16;  // RNE
  return (ushort_t)r;
}
__device__ inline float bflo(unsigned u) { return __uint_as_float(u << 16); }
__device__ inline float bfhi(unsigned u) { return __uint_as_float(u & 0xffff0000u); }

__device__ inline void gload_lds16(const void* src, void* ldsdst) {
  __builtin_amdgcn_global_load_lds((const __attribute__((address_space(1))) void*)src,
                                   (__attribute__((address_space(3))) void*)ldsdst, 16, 0, 0);
}

__device__ inline void cells_from_loc(float lx, float ly, int& c64, int& c32) {
  lx = fminf(fmaxf(lx, -1.f), 1.f) * 0.5f + 0.5f;
  ly = fminf(fmaxf(ly, -1.f), 1.f) * 0.5f + 0.5f;
  int cx = (int)fminf(fmaxf(rintf(lx * (WW - 1)), 0.f), (float)(WW - 1));
  int cy = (int)fminf(fmaxf(rintf(ly * (HH - 1)), 0.f), (float)(HH - 1));
  c64 = cx + cy * WW;
  int cx2 = (int)fminf(fmaxf(rintf(lx * (W2 - 1)), 0.f), (float)(W2 - 1));
  int cy2 = (int)fminf(fmaxf(rintf(ly * (H2 - 1)), 0.f), (float)(H2 - 1));
  c32 = cx2 + cy2 * W2;
}

// ---------- K1: cells + idx_agg_down output + counts (into packed bufs) + NRM ----------
__global__ __launch_bounds__(256) void k_prep(const float* __restrict__ loc, const int* __restrict__ idxagg,
                                              const float* __restrict__ aw,
                                              float* __restrict__ idx_out,
                                              unsigned* __restrict__ pck64, unsigned* __restrict__ pck32,
                                              unsigned* __restrict__ pckT, float* __restrict__ nrm) {
  int i = blockIdx.x * 256 + threadIdx.x;  // exactly B*N = 262144
  int b = i >> 12;
  int c64, c2;
  cells_from_loc(loc[2 * i], loc[2 * i + 1], c64, c2);
  idx_out[i] = (float)c2;
  atomicAdd(&pck64[(b << 12) + c64], 1u);
  atomicAdd(&pck32[(b << 10) + c2], 1u);
  atomicAdd(&pckT[(b << 12) + idxagg[i]], 1u);
  unsafeAtomicAdd(&nrm[(b << 12) + idxagg[i]], aw[i]);
}

// ---------- K2: bf16 transposed weights ----------
__global__ __launch_bounds__(256) void k_wprep(const float* __restrict__ convw, const float* __restrict__ skipw,
                                               ushort_t* __restrict__ wT, ushort_t* __restrict__ swT) {
  int e = blockIdx.x * 256 + threadIdx.x;  // 9*64*128 + 64*128 = 81920
  if (e < 9 * CCH * CO) {
    int co = e & 127, k = e >> 7;
    wT[co * 576 + k] = f2bf(convw[k * CO + co]);
  } else {
    int e2 = e - 9 * CCH * CO;
    int co = e2 & 127, k = e2 >> 7;
    swT[co * 64 + k] = f2bf(skipw[k * CO + co]);
  }
}

// ---------- scan helper: in-place exclusive scan; buf[i]: count -> (off<<16)|off ----------
__device__ void block_exscan_pack(unsigned* __restrict__ buf, int L) {
  __shared__ int partial[256];
  int tid = threadIdx.x;
  int per = L >> 8;
  int base = tid * per;
  int s = 0;
  for (int i = 0; i < per; i++) s += (int)buf[base + i];
  __syncthreads();  // protect partial[] from previous call
  partial[tid] = s;
  __syncthreads();
  for (int d = 1; d < 256; d <<= 1) {
    int v = (tid >= d) ? partial[tid - d] : 0;
    __syncthreads();
    partial[tid] += v;
    __syncthreads();
  }
  int run = (tid == 0) ? 0 : partial[tid - 1];
  for (int i = 0; i < per; i++) {
    int n = (int)buf[base + i];
    buf[base + i] = ((unsigned)run << 16) | (unsigned)run;
    run += n;
  }
}

// ---------- K3: per-batch prefix scans (3 sorts) ----------
__global__ __launch_bounds__(256) void k_scan(unsigned* __restrict__ pck64, unsigned* __restrict__ pckT,
                                              unsigned* __restrict__ pck32) {
  int b = blockIdx.x;  // 64
  block_exscan_pack(pck64 + ((size_t)b << 12), 4096);
  block_exscan_pack(pckT + ((size_t)b << 12), 4096);
  block_exscan_pack(pck32 + ((size_t)b << 10), 1024);
}

// ---------- K4: fill sorted packed lists; cursor = low 16 bits of pck ----------
__global__ __launch_bounds__(256) void k_fill(const float* __restrict__ loc, const int* __restrict__ idxagg,
                                              const float* __restrict__ aw,
                                              unsigned* __restrict__ pck64, unsigned* __restrict__ pckT,
                                              unsigned* __restrict__ pck32,
                                              ushort_t* __restrict__ list64, unsigned* __restrict__ listT,
                                              ushort_t* __restrict__ list32) {
  int i = blockIdx.x * 256 + threadIdx.x;  // B*N
  int b = i >> 12;
  int c64, c2;
  cells_from_loc(loc[2 * i], loc[2 * i + 1], c64, c2);
  int idx = idxagg[i];
  unsigned pos = atomicAdd(&pck64[(b << 12) + c64], 1u) & 0xffffu;
  list64[(b << 12) + pos] = (ushort_t)idx;                       // token index
  pos = atomicAdd(&pckT[(b << 12) + idx], 1u) & 0xffffu;
  listT[(b << 12) + pos] = ((unsigned)c2 << 16) | (unsigned)f2bf(aw[i]);  // {cell, aw-bf16}
  pos = atomicAdd(&pck32[(b << 10) + c2], 1u) & 0xffffu;
  list32[(b << 12) + pos] = (ushort_t)idx;                       // token index
}

// ---------- K4b: zero the padded map's border cells only (replaces 35 MB memset) ----------
__global__ __launch_bounds__(256) void k_border(ushort_t* __restrict__ xmb) {
  int t = blockIdx.x * 256 + threadIdx.x;  // exactly 64*260*16 = 266240
  int q = t & 15;
  int cell = (t >> 4) % 260;
  int b = t / (260 * 16);
  int r, c;
  if (cell < 66)       { r = 0;  c = cell; }
  else if (cell < 132) { r = 65; c = cell - 66; }
  else if (cell < 196) { r = cell - 132 + 1; c = 0; }
  else                 { r = cell - 196 + 1; c = 65; }
  *(uint2*)&xmb[(((size_t)(b * 66 + r)) * 66 + c) * 64 + q * 4] = make_uint2(0u, 0u);
}

// ---------- K5: token2map as GATHER (one wave per 64x64 cell), unroll-4 ----------
__global__ __launch_bounds__(256) void k_t2m(const float* __restrict__ x,
                                             const unsigned* __restrict__ pck64,
                                             const ushort_t* __restrict__ list64, ushort_t* __restrict__ xmb) {
  int blk = blockIdx.x;                       // 65536
  int sblk = (blk & 7) * 8192 + (blk >> 3);   // XCD swizzle: batch-contiguous per XCD
  int g = sblk * 4 + (threadIdx.x >> 6);      // cell id in [0, 64*4096)
  int lane = threadIdx.x & 63;
  int b = g >> 12, cell = g & 4095;
  unsigned v = pck64[g];
  int o = (int)(v >> 16), n = (int)(v & 0xffffu) - o;
  const ushort_t* lp = list64 + ((size_t)b << 12) + o;
  const float* xb = x + ((size_t)b << 18);
  float s0 = 0.f, s1 = 0.f, s2 = 0.f, s3 = 0.f;
  int i = 0;
  for (; i + 4 <= n; i += 4) {
    int i0 = lp[i], i1 = lp[i + 1], i2 = lp[i + 2], i3 = lp[i + 3];
    s0 += xb[(size_t)i0 * 64 + lane];
    s1 += xb[(size_t)i1 * 64 + lane];
    s2 += xb[(size_t)i2 * 64 + lane];
    s3 += xb[(size_t)i3 * 64 + lane];
  }
  for (; i < n; i++) s0 += xb[(size_t)lp[i] * 64 + lane];
  float avg = (s0 + s1 + s2 + s3) / ((float)n + EPSF);
  int r = cell >> 6, cc = cell & 63;
  xmb[(((size_t)(b * 66 + r + 1)) * 66 + cc + 1) * 64 + lane] = f2bf(avg);
}

// ---------- K6: conv 3x3 stride2 pad1 implicit GEMM (unchanged, verified) ----------
__global__ __launch_bounds__(256) void k_conv(const ushort_t* __restrict__ xmb, const ushort_t* __restrict__ wT,
                                              const float* __restrict__ cb, float* __restrict__ y) {
  __shared__ ushort_t A[2][4096];
  const int tid = threadIdx.x;
  const int wave = tid >> 6, lane = tid & 63;
  const int m0 = blockIdx.x * 128;

  f32x4 acc[2][8];
  {
    float bv[8];
#pragma unroll
    for (int nt = 0; nt < 8; nt++) bv[nt] = cb[nt * 16 + (lane & 15)];
#pragma unroll
    for (int mt = 0; mt < 2; mt++)
#pragma unroll
      for (int nt = 0; nt < 8; nt++) {
        f32x4 a; a[0] = bv[nt]; a[1] = bv[nt]; a[2] = bv[nt]; a[3] = bv[nt];
        acc[mt][nt] = a;
      }
  }

  const int srcslot = (((lane & 3) ^ ((lane >> 3) & 3))) * 8;
  int sb[2], soy[2], sox[2];
#pragma unroll
  for (int q = 0; q < 2; q++) {
    int r = wave * 32 + q * 16 + (lane >> 2);
    int s = m0 + r;
    sb[q] = s >> 10; soy[q] = (s >> 5) & 31; sox[q] = s & 31;
  }

  auto stage = [&](int ks, int buf) {
    int kp = ks >> 1, ci0 = (ks & 1) * 32;
    int ky = kp / 3, kx = kp - ky * 3;
#pragma unroll
    for (int q = 0; q < 2; q++) {
      int iy = 2 * soy[q] + ky, ix = 2 * sox[q] + kx;
      const ushort_t* src = xmb + (((size_t)sb[q] * 66 + iy) * 66 + ix) * 64 + ci0 + srcslot;
      gload_lds16(src, &A[buf][(wave * 32 + q * 16) * 32]);
    }
  };

  stage(0, 0);
  const int rdslotx = (lane >> 1) & 3;
  for (int ks = 0; ks < 18; ks++) {
    int buf = ks & 1;
    __syncthreads();
    if (ks < 17) stage(ks + 1, buf ^ 1);
    bf8 a[2];
#pragma unroll
    for (int mt = 0; mt < 2; mt++) {
      int r = wave * 32 + mt * 16 + (lane & 15);
      int slot = (lane >> 4) ^ rdslotx;
      a[mt] = *(const bf8*)&A[buf][r * 32 + slot * 8];
    }
    int k0 = ks * 32 + (lane >> 4) * 8;
#pragma unroll
    for (int nt = 0; nt < 8; nt++) {
      int co = nt * 16 + (lane & 15);
      bf8 bbf = *(const bf8*)&wT[co * 576 + k0];
      acc[0][nt] = __builtin_amdgcn_mfma_f32_16x16x32_bf16(a[0], bbf, acc[0][nt], 0, 0, 0);
      acc[1][nt] = __builtin_amdgcn_mfma_f32_16x16x32_bf16(a[1], bbf, acc[1][nt], 0, 0, 0);
    }
  }
#pragma unroll
  for (int mt = 0; mt < 2; mt++)
#pragma unroll
    for (int nt = 0; nt < 8; nt++) {
      int co = nt * 16 + (lane & 15);
#pragma unroll
      for (int j = 0; j < 4; j++) {
        int srow = m0 + wave * 32 + mt * 16 + (lane >> 4) * 4 + j;
        y[(size_t)srow * 128 + co] = acc[mt][nt][j];
      }
    }
}

// ---------- K7: FUSED xt = gather_m2t(y)/nrm + x@skip_w + BN partials; bf16 XT out ----------
// 64-token tile, 4096 blocks, 34 KB LDS (4 blocks/CU). Pipelined point gather, no atomics.
__global__ __launch_bounds__(256) void k_xt(const float* __restrict__ x, const ushort_t* __restrict__ swT,
                                            const float* __restrict__ y,
                                            const unsigned* __restrict__ listT, const unsigned* __restrict__ pckT,
                                            const float* __restrict__ nrm,
                                            ushort_t* __restrict__ XTB, float* __restrict__ BNP) {
  __shared__ float xg[64 * 128];   // 32 KB: x staging (first 16 KB) -> gather accum -> bf16 out (alias)
  __shared__ float nrminv[64];
  __shared__ float bnred[256];
  const int tid = threadIdx.x, wave = tid >> 6, lane = tid & 63;
  int blk = blockIdx.x;                       // 4096
  int sblk = (blk & 7) * 512 + (blk >> 3);    // XCD swizzle (8 batches per XCD)
  const int t0 = sblk * 64;
  const int b = t0 >> 12, lt0 = t0 & 4095;

  // ---- stage x tile (64x64 f32 = 16 KB), 16 chunks of 4 rows, swizzled 16B slots
#pragma unroll
  for (int q = 0; q < 4; q++) {
    int ch = wave * 4 + q;
    int r = ch * 4 + (lane >> 4);
    int sp = lane & 15;
    const float* src = x + ((size_t)(t0 + r)) * 64 + ((sp ^ (r & 7)) << 2);
    gload_lds16(src, (char*)xg + ch * 1024);
  }
  if (tid < 64) nrminv[tid] = 1.f / (nrm[(b << 12) + lt0 + tid] + EPSF);
  bnred[tid] = 0.f;
  __syncthreads();

  // ---- A fragments (f32 -> bf16)
  bf8 afr[2];
  {
    int r = wave * 16 + (lane & 15);
#pragma unroll
    for (int ks = 0; ks < 2; ks++) {
      int cs = ks * 4 + (lane >> 4);
      const float4 f0 = *(const float4*)&xg[r * 64 + (((2 * cs) ^ (r & 7)) << 2)];
      const float4 f1 = *(const float4*)&xg[r * 64 + (((2 * cs + 1) ^ (r & 7)) << 2)];
      bf8 v;
      v[0] = (short)f2bf(f0.x); v[1] = (short)f2bf(f0.y);
      v[2] = (short)f2bf(f0.z); v[3] = (short)f2bf(f0.w);
      v[4] = (short)f2bf(f1.x); v[5] = (short)f2bf(f1.y);
      v[6] = (short)f2bf(f1.z); v[7] = (short)f2bf(f1.w);
      afr[ks] = v;
    }
  }

  // ---- skip GEMM: wave computes rows [wave*16, wave*16+16) x 128 cols
  f32x4 acc[8];
#pragma unroll
  for (int nt = 0; nt < 8; nt++) { f32x4 z; z[0] = 0; z[1] = 0; z[2] = 0; z[3] = 0; acc[nt] = z; }
#pragma unroll
  for (int ks = 0; ks < 2; ks++)
#pragma unroll
    for (int nt = 0; nt < 8; nt++) {
      int co = nt * 16 + (lane & 15);
      bf8 bbf = *(const bf8*)&swT[co * 64 + ks * 32 + (lane >> 4) * 8];
      acc[nt] = __builtin_amdgcn_mfma_f32_16x16x32_bf16(afr[ks], bbf, acc[nt], 0, 0, 0);
    }

  __syncthreads();  // all waves' fragment reads done; xg reusable as gather accum

  // ---- zero own gather rows (swizzled float2 slots)
#pragma unroll
  for (int rr = 0; rr < 16; rr++) {
    *(float2*)&xg[(wave * 16 + rr) * 128 + ((2 * lane) ^ ((rr & 7) << 4))] = make_float2(0.f, 0.f);
  }

  // ---- m2t gather: pipelined; points for this wave's 16 tokens are contiguous in listT
  {
    int gtok = lt0 + wave * 16 + lane;
    int myoff = 0;
    if (lane <= 16) myoff = (gtok >= NN) ? NN : (int)(pckT[(b << 12) + gtok] >> 16);
    int pbeg = __shfl(myoff, 0, 64), pend = __shfl(myoff, 16, 64);
    const unsigned* ltb = listT + ((size_t)b << 12);
    const float* yb = y + ((size_t)b << 17);
    for (int chunk = pbeg; chunk < pend; chunk += 64) {
      int pid = chunk + lane;
      unsigned rec = 0u;
      if (pid < pend) rec = ltb[pid];
      int rr = 0;
#pragma unroll
      for (int j = 1; j <= 16; j++) rr += (pid >= __shfl(myoff, j, 64)) ? 1 : 0;
      int nrec = min(64, pend - chunk);
      int i = 0;
      for (; i + 4 <= nrec; i += 4) {
        float2 yv[4]; float vv[4]; int rw[4];
#pragma unroll
        for (int u = 0; u < 4; u++) {
          unsigned rb = (unsigned)__shfl((int)rec, i + u, 64);
          vv[u] = __uint_as_float(rb << 16);
          rw[u] = __shfl(rr, i + u, 64);
          yv[u] = *(const float2*)&yb[(size_t)(rb >> 16) * 128 + lane * 2];
        }
#pragma unroll
        for (int u = 0; u < 4; u++) {
          float2* p = (float2*)&xg[(wave * 16 + rw[u]) * 128 + ((2 * lane) ^ ((rw[u] & 7) << 4))];
          float2 cv = *p;
          cv.x += yv[u].x * vv[u]; cv.y += yv[u].y * vv[u];
          *p = cv;
        }
      }
      for (; i < nrec; i++) {
        unsigned rb = (unsigned)__shfl((int)rec, i, 64);
        float v = __uint_as_float(rb << 16);
        int rw0 = __shfl(rr, i, 64);
        float2 yv0 = *(const float2*)&yb[(size_t)(rb >> 16) * 128 + lane * 2];
        float2* p = (float2*)&xg[(wave * 16 + rw0) * 128 + ((2 * lane) ^ ((rw0 & 7) << 4))];
        float2 cv = *p;
        cv.x += yv0.x * v; cv.y += yv0.y * v;
        *p = cv;
      }
    }
  }

  // ---- epilogue: combine (acc in place) + BN partial sums
#pragma unroll
  for (int nt = 0; nt < 8; nt++) {
    int co = nt * 16 + (lane & 15);
    float s = 0.f, q = 0.f;
#pragma unroll
    for (int j = 0; j < 4; j++) {
      int r = wave * 16 + (lane >> 4) * 4 + j;
      float val = acc[nt][j] + xg[r * 128 + (co ^ ((r & 7) << 4))] * nrminv[r];
      acc[nt][j] = val;
      s += val; q += val * val;
    }
    s += __shfl_xor(s, 16, 64); s += __shfl_xor(s, 32, 64);
    q += __shfl_xor(q, 16, 64); q += __shfl_xor(q, 32, 64);
    if (lane < 16) {
      atomicAdd(&bnred[nt * 16 + lane], s);
      atomicAdd(&bnred[128 + nt * 16 + lane], q);
    }
  }
  __syncthreads();  // all gather-row reads done; xg reusable as bf16 tile

  // ---- pack bf16 into swizzled LDS tile, then one contiguous 16 KB coalesced store
  ushort_t* xto = (ushort_t*)xg;
#pragma unroll
  for (int nt = 0; nt < 8; nt++) {
    int co = nt * 16 + (lane & 15);
#pragma unroll
    for (int j = 0; j < 4; j++) {
      int r = wave * 16 + (lane >> 4) * 4 + j;
      xto[r * 128 + (co ^ ((r & 7) << 4))] = f2bf(acc[nt][j]);
    }
  }
  __syncthreads();
#pragma unroll
  for (int it = 0; it < 4; it++) {
    int q8 = (it * 256 + tid) * 8;  // ushort index in 64x128 tile
    int r = q8 >> 7, c = q8 & 127;
    uint4 vv = *(const uint4*)&xto[r * 128 + (c ^ ((r & 7) << 4))];
    *(uint4*)&XTB[((size_t)t0) * 128 + q8] = vv;
  }
  unsafeAtomicAdd(&BNP[(blk & 63) * 256 + tid], bnred[tid]);
}

// ---------- K8: reduce BN partials -> per-channel scale/shift ----------
__global__ void k_bnfin(const float* __restrict__ BNP, const float* __restrict__ gamma,
                        const float* __restrict__ beta, float* __restrict__ ss) {
  int c = threadIdx.x;  // 128
  float s = 0.f, q = 0.f;
#pragma unroll 4
  for (int k = 0; k < 64; k++) {
    s += BNP[k * 256 + c];
    q += BNP[k * 256 + 128 + c];
  }
  float n = (float)(BB * NN);
  float mean = s / n;
  float var = q / n - mean * mean;
  float sc = gamma[c] * rsqrtf(var + BNEPS);
  ss[c] = sc;
  ss[128 + c] = beta[c] - mean * sc;
}

// ---------- K9: conf + weight + fused x_act write (bf16 XT in) ----------
__global__ __launch_bounds__(256) void k_conf(const ushort_t* __restrict__ XTB, const float* __restrict__ ss,
                                              const float* __restrict__ confw, const float* __restrict__ confb,
                                              float* __restrict__ conf_out, float* __restrict__ wgt,
                                              float* __restrict__ xa) {
  int gid = blockIdx.x * 256 + threadIdx.x;
  int p = gid >> 6, lane = gid & 63;
  unsigned pw = *(const unsigned*)&XTB[(size_t)p * 128 + 2 * lane];
  const float2 sc = *(const float2*)&ss[2 * lane];
  const float2 sh = *(const float2*)&ss[128 + 2 * lane];
  float v0 = bflo(pw) * sc.x + sh.x;
  float v1 = bfhi(pw) * sc.y + sh.y;
  float2 xo; xo.x = fmaxf(v0, 0.f); xo.y = fmaxf(v1, 0.f);
  *(float2*)&xa[(size_t)p * 128 + 2 * lane] = xo;
  const float2 cw = *(const float2*)&confw[2 * lane];
  float s = v0 * cw.x + v1 * cw.y;
#pragma unroll
  for (int off = 32; off; off >>= 1) s += __shfl_down(s, off, 64);
  if (lane == 0) {
    float cf = s + confb[0];
    conf_out[p] = cf;
    wgt[p] = __expf(cf);
  }
}

// ---------- K10: cluster as GATHER (wave per 32x32 cell), bf16 XT rows, unroll-2 ----------
__global__ __launch_bounds__(256) void k_cluster(const ushort_t* __restrict__ XTB, const float* __restrict__ ss,
                                                 const float* __restrict__ wgt,
                                                 const unsigned* __restrict__ pck32,
                                                 const ushort_t* __restrict__ list32,
                                                 float* __restrict__ xd, float* __restrict__ cnrm) {
  int blk = blockIdx.x;                       // 16384
  int sblk = (blk & 7) * 2048 + (blk >> 3);   // XCD swizzle
  int wid = sblk * 4 + (threadIdx.x >> 6);
  int lane = threadIdx.x & 63;
  int b = wid >> 10;
  unsigned v = pck32[wid];
  int o = (int)(v >> 16), n = (int)(v & 0xffffu) - o;
  const ushort_t* lp = list32 + ((size_t)b << 12) + o;
  const float* wb = wgt + ((size_t)b << 12);
  const ushort_t* xtb = XTB + (((size_t)b) << 19);  // b*4096*128 ushorts
  const float2 sc = *(const float2*)&ss[2 * lane];
  const float2 sh = *(const float2*)&ss[128 + 2 * lane];
  float s0 = 0.f, s1 = 0.f, sv = 0.f;
  int i = 0;
  for (; i + 2 <= n; i += 2) {
    int i0 = lp[i], i1 = lp[i + 1];
    float v0 = wb[i0], v1 = wb[i1];
    unsigned p0 = *(const unsigned*)&xtb[(size_t)i0 * 128 + 2 * lane];
    unsigned p1 = *(const unsigned*)&xtb[(size_t)i1 * 128 + 2 * lane];
    s0 += (bflo(p0) * sc.x + sh.x) * v0 + (bflo(p1) * sc.x + sh.x) * v1;
    s1 += (bfhi(p0) * sc.y + sh.y) * v0 + (bfhi(p1) * sc.y + sh.y) * v1;
    sv += v0 + v1;
  }
  if (i < n) {
    int i0 = lp[i];
    float v0 = wb[i0];
    unsigned p0 = *(const unsigned*)&xtb[(size_t)i0 * 128 + 2 * lane];
    s0 += (bflo(p0) * sc.x + sh.x) * v0;
    s1 += (bfhi(p0) * sc.y + sh.y) * v0;
    sv += v0;
  }
  float inv = 1.f / (sv + EPSF);
  float2 o2; o2.x = fmaxf(s0 * inv, 0.f); o2.y = fmaxf(s1 * inv, 0.f);
  *(float2*)&xd[(size_t)wid * 128 + 2 * lane] = o2;
  if (lane == 0) cnrm[wid] = sv;
}

// ---------- K11: agg_weight_down (pre-norm) + per-batch max ----------
__global__ __launch_bounds__(256) void k_awd(const float* __restrict__ loc, const float* __restrict__ wgt,
                                             const float* __restrict__ aw, const int* __restrict__ idxagg,
                                             const float* __restrict__ cnrm,
                                             float* __restrict__ awd, int* __restrict__ maxb) {
  int p = blockIdx.x * 256 + threadIdx.x;  // B*N
  int b = p >> 12;
  int c64, c2;
  cells_from_loc(loc[2 * p], loc[2 * p + 1], c64, c2);
  float v = wgt[(b << 12) + idxagg[p]];
  float wt = v / (cnrm[(b << 10) + c2] + EPSF);
  float a = aw[p] * wt;
  awd[p] = a;
  float m = a;
#pragma unroll
  for (int off = 32; off; off >>= 1) m = fmaxf(m, __shfl_down(m, off, 64));
  if ((threadIdx.x & 63) == 0) atomicMax(&maxb[b], __float_as_int(m));  // all values > 0
}

// ---------- K12: normalize awd ----------
__global__ __launch_bounds__(256) void k_awdnorm(float* __restrict__ awd, const int* __restrict__ maxb) {
  int p = blockIdx.x * 256 + threadIdx.x;
  int b = p >> 12;
  awd[p] = awd[p] / __int_as_float(maxb[b]);
}

extern "C" void kernel_launch(void* const* d_in, const int* in_sizes, int n_in,
                              void* d_out, int out_size, void* d_ws, size_t ws_size,
                              hipStream_t stream) {
  (void)in_sizes; (void)n_in; (void)out_size;
  const float* x      = (const float*)d_in[0];
  const float* loc    = (const float*)d_in[1];
  const int*   idxagg = (const int*)  d_in[2];
  const float* aw     = (const float*)d_in[3];
  const float* convw  = (const float*)d_in[4];
  const float* convb  = (const float*)d_in[5];
  const float* skipw  = (const float*)d_in[6];
  const float* gamma  = (const float*)d_in[7];
  const float* beta   = (const float*)d_in[8];
  const float* confw  = (const float*)d_in[9];
  const float* confb  = (const float*)d_in[10];

  char* ws = (char*)d_ws;
  ushort_t* XTB   = (ushort_t*)(ws + 0);          // 67,108,864 (bf16 xt)
  float*    Y     = (float*)  (ws + 67108864);    // 33,554,432
  ushort_t* XMB   = (ushort_t*)(ws + 100663296);  // 35,684,352 (padded 66x66 bf16 map)
  // post-conv aliases inside XMB region (all written strictly after k_conv):
  float*    WGT   = (float*)  (ws + 100663296);   // 1,048,576
  float*    CNRM  = (float*)  (ws + 101711872);   // 262,144
  float*    BNP   = (float*)  (ws + 101974016);   // 65,536
  float*    SS    = (float*)  (ws + 102039552);   // 1,024
  int*      MAXB  = (int*)    (ws + 102040576);   // 256
  ushort_t* WT    = (ushort_t*)(ws + 136347648);  // 147,456
  ushort_t* SWT   = (ushort_t*)(ws + 136495104);  // 16,384
  float*    NRM   = (float*)  (ws + 136511488);   // 1,048,576
  unsigned* PCK64 = (unsigned*)(ws + 137560064);  // 1,048,576  (off<<16 | cursor)
  ushort_t* LIST64= (ushort_t*)(ws + 138608640);  // 524,288    (token idx u16)
  unsigned* PCKT  = (unsigned*)(ws + 139132928);  // 1,048,576
  unsigned* LISTT = (unsigned*)(ws + 140181504);  // 1,048,576  (cell<<16 | aw-bf16)
  unsigned* PCK32 = (unsigned*)(ws + 141230080);  // 262,144
  ushort_t* LIST32= (ushort_t*)(ws + 141492224);  // 524,288    (token idx u16)
  if (ws_size < 142016512) return;  // insufficient workspace -> visible failure

  float* out    = (float*)d_out;
  float* O_XD   = out;               // x_down: 8,388,608 floats
  float* O_IDX  = out + 8388608;     // idx_agg_down (as float): 262,144
  float* O_AWD  = out + 8650752;     // agg_weight_down: 262,144
  float* XA     = out + 8912896;     // x_act: 33,554,432 floats
  float* O_CONF = out + 42467328;    // conf: 262,144

  hipMemsetAsync(PCK64, 0, 1048576, stream);
  hipMemsetAsync(PCKT, 0, 1048576, stream);
  hipMemsetAsync(PCK32, 0, 262144, stream);
  hipMemsetAsync(NRM, 0, 1048576, stream);

  k_prep   <<<1024,  256, 0, stream>>>(loc, idxagg, aw, O_IDX, PCK64, PCK32, PCKT, NRM);
  k_wprep  <<<320,   256, 0, stream>>>(convw, skipw, WT, SWT);
  k_scan   <<<64,    256, 0, stream>>>(PCK64, PCKT, PCK32);
  k_fill   <<<1024,  256, 0, stream>>>(loc, idxagg, aw, PCK64, PCKT, PCK32, LIST64, LISTT, LIST32);
  k_border <<<1040,  256, 0, stream>>>(XMB);
  k_t2m    <<<65536, 256, 0, stream>>>(x, PCK64, LIST64, XMB);
  k_conv   <<<512,   256, 0, stream>>>(XMB, WT, convb, Y);
  // XMB dead from here; its region hosts WGT/CNRM/BNP/SS/MAXB
  hipMemsetAsync(BNP, 0, 65536, stream);
  hipMemsetAsync(MAXB, 0, 256, stream);
  k_xt     <<<4096,  256, 0, stream>>>(x, SWT, Y, LISTT, PCKT, NRM, XTB, BNP);
  k_bnfin  <<<1,     128, 0, stream>>>(BNP, gamma, beta, SS);
  k_conf   <<<65536, 256, 0, stream>>>(XTB, SS, confw, confb, O_CONF, WGT, XA);
  k_cluster<<<16384, 256, 0, stream>>>(XTB, SS, WGT, PCK32, LIST32, O_XD, CNRM);
  k_awd    <<<1024,  256, 0, stream>>>(loc, WGT, aw, idxagg, CNRM, O_AWD, MAXB);
  k_awdnorm<<<1024,  256, 0, stream>>>(O_AWD, MAXB);
}